// Round 5
// baseline (659.945 us; speedup 1.0000x reference)
//
#include <hip/hip_runtime.h>

// Encoder: D=4, L=16, C=64, H=W=128.
// Math: softmax_j(A_i+B_j+ba)==softmax_j(B_j); attn identical for all i;
// B = conv5(h,Weff) as GEMM into 25 bf16 tap planes T + shift-add.
// R4: bucketed stat accumulators. R5: prep 64 blocks. R6: weight frags
// direct from global. R7: rotation LDS swizzle, wave acc-reduce, a-plane.
// R8 (this): (1) no x copy — depth 0 reads x_in directly, stats-only
// kernel replaces copystats (-128MB); (2) T planes bf16 (-26MB/depth);
// (3) vb/ffn at 64 px/block (halved per-block phase chain, 2x blocks) to
// attack the latency-chain: phases are dependent global-load chains and
// occupancy sweeps (18/28/18%) showed residency wasn't the lever.

#define HW 16384
#define CHW 1048576
#define NB 64  // stat buckets; each bucket = 32 floats = one 128B line

typedef unsigned short u16;
typedef __attribute__((ext_vector_type(8))) short bf16x8;
typedef __attribute__((ext_vector_type(4))) float f32x4;

static __device__ __forceinline__ u16 f2bf(float f) {
  union { float f; unsigned int u; } v; v.f = f;
  unsigned int r = v.u + 0x7fffu + ((v.u >> 16) & 1u);
  return (u16)(r >> 16);
}
static __device__ __forceinline__ float bf2f(u16 h) {
  union { unsigned int u; float f; } v; v.u = ((unsigned int)h) << 16;
  return v.f;
}
// LN stats from bucketed accumulators, wave-parallel: lane b loads bucket
// b's partial (one float2), butterfly-reduce across 64 lanes.
static __device__ __forceinline__ void ln_from_acc_wave(
    const float* acc, int l, int lane, float& mu, float& r) {
  const float invN = 1.f / 1048576.f;
  float2 v = *(const float2*)(acc + lane * 32 + 2 * l);
  float s = v.x, q = v.y;
#pragma unroll
  for (int off = 32; off > 0; off >>= 1) {
    s += __shfl_xor(s, off);
    q += __shfl_xor(q, off);
  }
  mu = s * invN;
  r = rsqrtf(q * invN - mu * mu + 1e-5f);
}

// ---- precompute bf16 MFMA fragment packs (layout identical for A/B use):
// pack[((t0*KT+kt)*64+lane)*8+j] = W[m=t0*16+(lane&15)][k=kt*32+(lane>>4)*8+j]
__global__ __launch_bounds__(256) void prep_kernel(
    const float* __restrict__ Wa, const float* __restrict__ Wk,
    const float* __restrict__ Wv, const float* __restrict__ W1,
    const float* __restrict__ W2, u16* __restrict__ w1pk,
    u16* __restrict__ w2pk, u16* __restrict__ wvpk, u16* __restrict__ wepk) {
  int d = blockIdx.x;
  int t = blockIdx.y * 256 + threadIdx.x;  // 0..4095
  const int STR = 256 * 16;
  const float* WaK = Wa + ((size_t)d * 128 + 64) * 25;
  const float* Wkd = Wk + d * 4096;
  for (int idx = t; idx < 2048; idx += STR) {  // Weff: m=tap(32), k=ci(64)
    int frag = idx >> 9, lane = (idx >> 3) & 63, j = idx & 7;
    int mt = frag >> 1, kt = frag & 1;
    int tap = mt * 16 + (lane & 15);
    int ci = kt * 32 + (lane >> 4) * 8 + j;
    float s = 0.f;
    if (tap < 25)
      for (int co = 0; co < 64; ++co)
        s = fmaf(WaK[co * 25 + tap], Wkd[co * 64 + ci], s);
    wepk[d * 2048 + idx] = f2bf(s);
  }
  const float* Wvd = Wv + d * 4096;
  for (int idx = t; idx < 4096; idx += STR) {  // Wv: m=co(64), k=ci(64)
    int frag = idx >> 9, lane = (idx >> 3) & 63, j = idx & 7;
    int mt = frag >> 1, kt = frag & 1;
    int co = mt * 16 + (lane & 15);
    int ci = kt * 32 + (lane >> 4) * 8 + j;
    wvpk[d * 4096 + idx] = f2bf(Wvd[co * 64 + ci]);
  }
  const float* W1d = W1 + d * 8192;
  for (int idx = t; idx < 8192; idx += STR) {  // W1: m=o(128), k=ci(64)
    int frag = idx >> 9, lane = (idx >> 3) & 63, j = idx & 7;
    int mt = frag >> 1, kt = frag & 1;
    int o = mt * 16 + (lane & 15);
    int ci = kt * 32 + (lane >> 4) * 8 + j;
    w1pk[d * 8192 + idx] = f2bf(W1d[o * 64 + ci]);
  }
  const float* W2d = W2 + d * 8192;
  for (int idx = t; idx < 8192; idx += STR) {  // W2: m=c(64), k=o(128)
    int frag = idx >> 9, lane = (idx >> 3) & 63, j = idx & 7;
    int mt2 = frag >> 2, kt2 = frag & 3;
    int c = mt2 * 16 + (lane & 15);
    int o = kt2 * 32 + (lane >> 4) * 8 + j;
    w2pk[d * 8192 + idx] = f2bf(W2d[c * 128 + o]);
  }
}

// ---- per-frame stats of x_in (bucketed); no copy ----
__global__ __launch_bounds__(256) void stats_kernel(
    const float* __restrict__ xin, float* __restrict__ acc) {
  int tid = threadIdx.x;
  size_t base = (size_t)blockIdx.x * 4096;
  const float4* in4 = (const float4*)(xin + base);
  float s = 0.f, q = 0.f;
#pragma unroll
  for (int k = 0; k < 4; ++k) {
    float4 v = in4[k * 256 + tid];
    s += v.x + v.y + v.z + v.w;
    q = fmaf(v.x, v.x, q); q = fmaf(v.y, v.y, q);
    q = fmaf(v.z, v.z, q); q = fmaf(v.w, v.w, q);
  }
#pragma unroll
  for (int off = 32; off > 0; off >>= 1) {
    s += __shfl_down(s, off); q += __shfl_down(q, off);
  }
  __shared__ float ls[4], lq[4];
  int wave = tid >> 6;
  if ((tid & 63) == 0) { ls[wave] = s; lq[wave] = q; }
  __syncthreads();
  if (tid == 0) {
    int frame = blockIdx.x >> 8;
    int bkt = blockIdx.x & (NB - 1);
    atomicAdd(&acc[bkt * 32 + frame * 2], ls[0] + ls[1] + ls[2] + ls[3]);
    atomicAdd(&acc[bkt * 32 + frame * 2 + 1], lq[0] + lq[1] + lq[2] + lq[3]);
  }
}

// ---- fused LN1 + V GEMM + T GEMM, 64 px/block ----
// LDS: hb[64][72] u16 chunk-rotated (9216 B). Weight frags direct-global.
__global__ __launch_bounds__(256) void vb_kernel(
    const float* __restrict__ x, const float* __restrict__ g,
    const float* __restrict__ bln, const u16* __restrict__ wvp_g,
    const float* __restrict__ bv, const u16* __restrict__ wep_g,
    const float* __restrict__ accA, float* __restrict__ accBz,
    u16* __restrict__ Vb, u16* __restrict__ T) {
  __shared__ __align__(16) char lds[9216];
  u16* hb = (u16*)lds;
  int tid = threadIdx.x;
  int l = blockIdx.y;
  int p0 = blockIdx.x << 6;
  // zero accB buckets for attnc_update (safe: no other kernel concurrent)
  if (blockIdx.x == 0 && blockIdx.y == 0)
    for (int i = tid; i < NB * 32; i += 256) accBz[i] = 0.f;
  int lane = tid & 63;
  float mu, r;
  ln_from_acc_wave(accA, l, lane, mu, r);

  // stage h[64px][64ci] bf16, chunk-rotated writes; thread=(pq,cg)
  {
    int pq = tid & 15, cg = tid >> 4;
    int px = pq * 4, c0 = cg * 4;
    float vv[4][4];
#pragma unroll
    for (int i = 0; i < 4; ++i) {
      int c = c0 + i;
      size_t gi = (((size_t)l * 64 + c) << 14) + p0 + px;
      int li = (c << 14) + p0 + px;
      float4 xv = *(const float4*)(x + gi);
      float4 gv = *(const float4*)(g + li);
      float4 bb = *(const float4*)(bln + li);
      vv[i][0] = (xv.x - mu) * r * gv.x + bb.x;
      vv[i][1] = (xv.y - mu) * r * gv.y + bb.y;
      vv[i][2] = (xv.z - mu) * r * gv.z + bb.z;
      vv[i][3] = (xv.w - mu) * r * gv.w + bb.w;
    }
#pragma unroll
    for (int k = 0; k < 4; ++k) {
      int row = px + k;
      int col = ((((c0 >> 3) + (row >> 2)) & 7) << 3) | (c0 & 7);
      ushort4 hv;
      hv.x = f2bf(vv[0][k]); hv.y = f2bf(vv[1][k]);
      hv.z = f2bf(vv[2][k]); hv.w = f2bf(vv[3][k]);
      *(ushort4*)(hb + row * 72 + col) = hv;
    }
  }
  __syncthreads();

  int wv = tid >> 6;
  int ln15 = lane & 15, quad = lane >> 4;

  // each wave owns px-tile wv; A = h rows, B = weight frags from global
  bf16x8 ah[2];
  int px = wv * 16 + ln15;
#pragma unroll
  for (int kt = 0; kt < 2; ++kt) {
    int slot = ((kt * 4 + quad) + (px >> 2)) & 7;
    ah[kt] = *(const bf16x8*)(hb + px * 72 + (slot << 3));
  }
  const bf16x8* wvg = (const bf16x8*)wvp_g;  // frag f at wvg[f*64+lane]
  const bf16x8* weg = (const bf16x8*)wep_g;

  f32x4 accV[4], accT[2];
#pragma unroll
  for (int nt = 0; nt < 4; ++nt) accV[nt] = (f32x4){0.f, 0.f, 0.f, 0.f};
#pragma unroll
  for (int nt = 0; nt < 2; ++nt) accT[nt] = (f32x4){0.f, 0.f, 0.f, 0.f};
#pragma unroll
  for (int nt = 0; nt < 4; ++nt) {
    bf16x8 b0 = wvg[(nt * 2 + 0) * 64 + lane];
    bf16x8 b1w = wvg[(nt * 2 + 1) * 64 + lane];
    accV[nt] = __builtin_amdgcn_mfma_f32_16x16x32_bf16(ah[0], b0, accV[nt],
                                                       0, 0, 0);
    accV[nt] = __builtin_amdgcn_mfma_f32_16x16x32_bf16(ah[1], b1w, accV[nt],
                                                       0, 0, 0);
  }
#pragma unroll
  for (int nt = 0; nt < 2; ++nt) {
    bf16x8 b0 = weg[(nt * 2 + 0) * 64 + lane];
    bf16x8 b1w = weg[(nt * 2 + 1) * 64 + lane];
    accT[nt] = __builtin_amdgcn_mfma_f32_16x16x32_bf16(ah[0], b0, accT[nt],
                                                       0, 0, 0);
    accT[nt] = __builtin_amdgcn_mfma_f32_16x16x32_bf16(ah[1], b1w, accT[nt],
                                                       0, 0, 0);
  }

  // epilogue: D rows = px (quad*4+rj) -> ushort4 stores (V and T bf16)
  int pxb = p0 + wv * 16 + quad * 4;
#pragma unroll
  for (int nt = 0; nt < 4; ++nt) {
    int c = nt * 16 + ln15;
    float bvc = bv[c];
    ushort4 o;
    o.x = f2bf(accV[nt][0] + bvc);
    o.y = f2bf(accV[nt][1] + bvc);
    o.z = f2bf(accV[nt][2] + bvc);
    o.w = f2bf(accV[nt][3] + bvc);
    *(ushort4*)(Vb + (((size_t)l * 64 + c) << 14) + pxb) = o;
  }
#pragma unroll
  for (int nt = 0; nt < 2; ++nt) {
    int tap = nt * 16 + ln15;
    if (tap < 25) {
      ushort4 o;
      o.x = f2bf(accT[nt][0]); o.y = f2bf(accT[nt][1]);
      o.z = f2bf(accT[nt][2]); o.w = f2bf(accT[nt][3]);
      *(ushort4*)(T + (((size_t)l * 25 + tap) << 14) + pxb) = o;
    }
  }
}

// ---- B[l][p] = sum_tap T[l][tap][p + off(tap)] (T bf16) ----
__global__ __launch_bounds__(256) void bconv_kernel(
    const u16* __restrict__ T, float* __restrict__ B) {
  int gid = blockIdx.x * 256 + threadIdx.x;
  int l = gid >> 14, p = gid & 16383;
  int y = p >> 7, xx = p & 127;
  float s = 0.f;
#pragma unroll
  for (int dy = 0; dy < 5; ++dy) {
    int yy = y + dy - 2;
    if (yy < 0 || yy > 127) continue;
#pragma unroll
    for (int dx = 0; dx < 5; ++dx) {
      int xc = xx + dx - 2;
      if (xc < 0 || xc > 127) continue;
      s += bf2f(T[(((size_t)l * 25 + dy * 5 + dx) << 14) + (yy << 7) + xc]);
    }
  }
  B[gid] = s;
}

// ---- fused: softmax over j, attnc -> a-plane write + stats of (x+a) ----
// NO x writeback (a is frame-independent; ffn folds x+a). grid 1024x256.
__global__ __launch_bounds__(256) void attnc_update_kernel(
    const float* __restrict__ x, const u16* __restrict__ Vb,
    const float* __restrict__ B, float* __restrict__ ap,
    float* __restrict__ accB, float* __restrict__ accAz) {
  int tid = threadIdx.x;
  if (blockIdx.x == 0)  // zero accA buckets for ffn
    for (int i = tid; i < NB * 32; i += 256) accAz[i] = 0.f;
  int gid = blockIdx.x * 256 + tid;
  int c = gid >> 12;
  int p4 = (gid & 4095) << 2;
  float4 bj[16];
  float4 m = {-1e30f, -1e30f, -1e30f, -1e30f};
#pragma unroll
  for (int j = 0; j < 16; ++j) {
    bj[j] = *(const float4*)(B + (j << 14) + p4);
    m.x = fmaxf(m.x, bj[j].x); m.y = fmaxf(m.y, bj[j].y);
    m.z = fmaxf(m.z, bj[j].z); m.w = fmaxf(m.w, bj[j].w);
  }
  float4 sum = {0.f, 0.f, 0.f, 0.f};
#pragma unroll
  for (int j = 0; j < 16; ++j) {
    bj[j].x = __expf(bj[j].x - m.x); bj[j].y = __expf(bj[j].y - m.y);
    bj[j].z = __expf(bj[j].z - m.z); bj[j].w = __expf(bj[j].w - m.w);
    sum.x += bj[j].x; sum.y += bj[j].y; sum.z += bj[j].z; sum.w += bj[j].w;
  }
  float4 a = {0.f, 0.f, 0.f, 0.f};
#pragma unroll
  for (int j = 0; j < 16; ++j) {
    ushort4 v = *(const ushort4*)(Vb + (((size_t)j * 64 + c) << 14) + p4);
    a.x = fmaf(bj[j].x, bf2f(v.x), a.x);
    a.y = fmaf(bj[j].y, bf2f(v.y), a.y);
    a.z = fmaf(bj[j].z, bf2f(v.z), a.z);
    a.w = fmaf(bj[j].w, bf2f(v.w), a.w);
  }
  a.x /= sum.x; a.y /= sum.y; a.z /= sum.z; a.w /= sum.w;
  *(float4*)(ap + ((size_t)c << 14) + p4) = a;
  // per-frame stats of (x + a), read-only x
  float sf[16], qf[16];
#pragma unroll
  for (int f = 0; f < 16; ++f) {
    const float4* xp =
        (const float4*)(x + ((size_t)f << 20) + ((size_t)c << 14) + p4);
    float4 v = *xp;
    v.x += a.x; v.y += a.y; v.z += a.z; v.w += a.w;
    sf[f] = v.x + v.y + v.z + v.w;
    float q = 0.f;
    q = fmaf(v.x, v.x, q); q = fmaf(v.y, v.y, q);
    q = fmaf(v.z, v.z, q); q = fmaf(v.w, v.w, q);
    qf[f] = q;
  }
#pragma unroll
  for (int off = 32; off > 0; off >>= 1) {
#pragma unroll
    for (int f = 0; f < 16; ++f) {
      sf[f] += __shfl_down(sf[f], off);
      qf[f] += __shfl_down(qf[f], off);
    }
  }
  __shared__ float lsq[4][32];
  int wv = tid >> 6;
  if ((tid & 63) == 0) {
#pragma unroll
    for (int f = 0; f < 16; ++f) {
      lsq[wv][2 * f] = sf[f];
      lsq[wv][2 * f + 1] = qf[f];
    }
  }
  __syncthreads();
  if (tid < 32) {
    int bkt = blockIdx.x & (NB - 1);
    atomicAdd(&accB[bkt * 32 + tid],
              lsq[0][tid] + lsq[1][tid] + lsq[2][tid] + lsq[3][tid]);
  }
}

// ---- fused attn-add + LN2 + FFN + residual + stats, 64 px/block ----
// h = LN(xr+a); xw = xr + a + W2*leaky(W1*h+b1) + b2.
// LDS: hb[64][72] rotated (9216); f1[64][128] swz overlays (16384 total).
__global__ __launch_bounds__(256) void ffn_kernel(
    const float* __restrict__ xr, float* __restrict__ xw,
    const float* __restrict__ ap, const float* __restrict__ g,
    const float* __restrict__ bln, const u16* __restrict__ w1p_g,
    const float* __restrict__ b1, const u16* __restrict__ w2p_g,
    const float* __restrict__ b2, const float* __restrict__ accB,
    float* __restrict__ accA) {
  __shared__ __align__(16) char lds[16384];
  u16* hb = (u16*)lds;  // [64][72] chunk-rotated
  u16* f1 = (u16*)lds;  // [64][128] swizzled, overlays hb after sync2

  int tid = threadIdx.x;
  int P0 = blockIdx.x << 6;
  int l = P0 >> 14;
  int p0 = P0 & 16383;
  int lane = tid & 63;
  float mu, r;
  ln_from_acc_wave(accB, l, lane, mu, r);

  // stage h = LN(x + a) (chunk-rotated writes); thread=(pq,cg)
  {
    int pq = tid & 15, cg = tid >> 4;
    int px = pq * 4, c0 = cg * 4;
    float vv[4][4];
#pragma unroll
    for (int i = 0; i < 4; ++i) {
      int c = c0 + i;
      size_t gi = (((size_t)l * 64 + c) << 14) + p0 + px;
      int li = (c << 14) + p0 + px;
      float4 xv = *(const float4*)(xr + gi);
      float4 av = *(const float4*)(ap + li);
      float4 gv = *(const float4*)(g + li);
      float4 bb = *(const float4*)(bln + li);
      vv[i][0] = (xv.x + av.x - mu) * r * gv.x + bb.x;
      vv[i][1] = (xv.y + av.y - mu) * r * gv.y + bb.y;
      vv[i][2] = (xv.z + av.z - mu) * r * gv.z + bb.z;
      vv[i][3] = (xv.w + av.w - mu) * r * gv.w + bb.w;
    }
#pragma unroll
    for (int k = 0; k < 4; ++k) {
      int row = px + k;
      int col = ((((c0 >> 3) + (row >> 2)) & 7) << 3) | (c0 & 7);
      ushort4 hv;
      hv.x = f2bf(vv[0][k]); hv.y = f2bf(vv[1][k]);
      hv.z = f2bf(vv[2][k]); hv.w = f2bf(vv[3][k]);
      *(ushort4*)(hb + row * 72 + col) = hv;
    }
  }
  __syncthreads();

  int wv = tid >> 6;
  int ln15 = lane & 15, quad = lane >> 4;
  int px = wv * 16 + ln15;

  // h fragments -> registers (rotated chunk reads); wave owns px-tile wv
  bf16x8 bh[2];
#pragma unroll
  for (int kt = 0; kt < 2; ++kt) {
    int slot = ((kt * 4 + quad) + (px >> 2)) & 7;
    bh[kt] = *(const bf16x8*)(hb + px * 72 + (slot << 3));
  }
  __syncthreads();  // all hb reads drained; f1 may now overwrite

  const bf16x8* w1g = (const bf16x8*)w1p_g;  // frag f at w1g[f*64+lane]
  const bf16x8* w2g = (const bf16x8*)w2p_g;
  int swz = (px & 7) * 8;

  // GEMM1 per o-tile mt: load 2 W1 frags, 2 MFMAs, bias+leaky, f1 write
#pragma unroll
  for (int mt = 0; mt < 8; ++mt) {
    bf16x8 a1a = w1g[(mt * 2 + 0) * 64 + lane];
    bf16x8 a1b = w1g[(mt * 2 + 1) * 64 + lane];
    f32x4 acc = (f32x4){0.f, 0.f, 0.f, 0.f};
    acc = __builtin_amdgcn_mfma_f32_16x16x32_bf16(a1a, bh[0], acc, 0, 0, 0);
    acc = __builtin_amdgcn_mfma_f32_16x16x32_bf16(a1b, bh[1], acc, 0, 0, 0);
    int o0 = mt * 16 + quad * 4;
    float4 b1v = *(const float4*)(b1 + o0);
    float fv[4];
#pragma unroll
    for (int rj = 0; rj < 4; ++rj) {
      float f = acc[rj] + ((const float*)&b1v)[rj];
      fv[rj] = fmaxf(f, 0.01f * f);
    }
    int col = ((o0 & ~7) ^ swz) + (o0 & 7);
    ushort4 ov;
    ov.x = f2bf(fv[0]); ov.y = f2bf(fv[1]);
    ov.z = f2bf(fv[2]); ov.w = f2bf(fv[3]);
    *(ushort4*)(f1 + px * 128 + col) = ov;
  }
  __syncthreads();

  // GEMM2 transposed: D[px][c], A=f1 rows, B=W2 frags direct from global
  bf16x8 a2[4];
#pragma unroll
  for (int kt = 0; kt < 4; ++kt)
    a2[kt] = *(const bf16x8*)(f1 + px * 128 + ((kt * 32 + quad * 8) ^ swz));
  f32x4 acc2[4];
#pragma unroll
  for (int nt = 0; nt < 4; ++nt) acc2[nt] = (f32x4){0.f, 0.f, 0.f, 0.f};
#pragma unroll
  for (int nt = 0; nt < 4; ++nt) {
#pragma unroll
    for (int kt = 0; kt < 4; ++kt) {
      bf16x8 bw = w2g[(nt * 4 + kt) * 64 + lane];
      acc2[nt] = __builtin_amdgcn_mfma_f32_16x16x32_bf16(a2[kt], bw, acc2[nt],
                                                         0, 0, 0);
    }
  }

  // epilogue: v = xr + a + ffn_out -> xw; float4 + stats
  float s = 0.f, q = 0.f;
  int pxb = p0 + wv * 16 + quad * 4;
#pragma unroll
  for (int nt = 0; nt < 4; ++nt) {
    int c = nt * 16 + ln15;
    float b2c = b2[c];
    size_t gi = (((size_t)l * 64 + c) << 14) + pxb;
    float4 v = *(const float4*)(xr + gi);
    float4 av = *(const float4*)(ap + ((size_t)c << 14) + pxb);
    v.x += av.x + acc2[nt][0] + b2c;
    v.y += av.y + acc2[nt][1] + b2c;
    v.z += av.z + acc2[nt][2] + b2c;
    v.w += av.w + acc2[nt][3] + b2c;
    *(float4*)(xw + gi) = v;
    s += v.x + v.y + v.z + v.w;
    q = fmaf(v.x, v.x, q); q = fmaf(v.y, v.y, q);
    q = fmaf(v.z, v.z, q); q = fmaf(v.w, v.w, q);
  }
#pragma unroll
  for (int off = 32; off > 0; off >>= 1) {
    s += __shfl_down(s, off); q += __shfl_down(q, off);
  }
  if (lane == 0) {
    int bkt = blockIdx.x & (NB - 1);
    atomicAdd(&accA[bkt * 32 + l * 2], s);
    atomicAdd(&accA[bkt * 32 + l * 2 + 1], q);
  }
}

extern "C" void kernel_launch(void* const* d_in, const int* in_sizes, int n_in,
                              void* d_out, int out_size, void* d_ws,
                              size_t ws_size, hipStream_t stream) {
  const float* x_in = (const float*)d_in[0];
  const float* ln1_g = (const float*)d_in[1];
  const float* ln1_b = (const float*)d_in[2];
  const float* Wk = (const float*)d_in[5];
  const float* Wv = (const float*)d_in[7];
  const float* bv = (const float*)d_in[8];
  const float* Wa = (const float*)d_in[9];
  const float* ln2_g = (const float*)d_in[11];
  const float* ln2_b = (const float*)d_in[12];
  const float* W1 = (const float*)d_in[13];
  const float* b1 = (const float*)d_in[14];
  const float* W2 = (const float*)d_in[15];
  const float* b2 = (const float*)d_in[16];

  float* xbuf = (float*)d_out;
  char* wsb = (char*)d_ws;
  u16* Vb = (u16*)wsb;                       // 33,554,432 B
  u16* T = (u16*)(wsb + 33554432);           // 13,107,200 B (bf16 taps)
  float* aplane = (float*)(wsb + 46661632);  // 4,194,304 B
  float* Bbuf = (float*)(wsb + 50855936);    // 1,048,576 B
  u16* w1pk = (u16*)(wsb + 51904512);        // 65,536 B
  u16* w2pk = (u16*)(wsb + 51970048);        // 65,536 B
  u16* wvpk = (u16*)(wsb + 52035584);        // 32,768 B
  u16* wepk = (u16*)(wsb + 52068352);        // 16,384 B
  float* accA = (float*)(wsb + 52084736);    // 8,192 B
  float* accB = (float*)(wsb + 52092928);    // 8,192 B

  hipMemsetAsync(accA, 0, 16384, stream);  // accA + accB
  prep_kernel<<<dim3(4, 16), 256, 0, stream>>>(Wa, Wk, Wv, W1, W2, w1pk, w2pk,
                                               wvpk, wepk);
  stats_kernel<<<4096, 256, 0, stream>>>(x_in, accA);

  const float* xr = x_in;
  for (int d = 0; d < 4; ++d) {
    vb_kernel<<<dim3(256, 16), 256, 0, stream>>>(
        xr, ln1_g + (size_t)d * CHW, ln1_b + (size_t)d * CHW, wvpk + d * 4096,
        bv + d * 64, wepk + d * 2048, accA, accB, Vb, T);
    bconv_kernel<<<1024, 256, 0, stream>>>(T, Bbuf);
    attnc_update_kernel<<<1024, 256, 0, stream>>>(xr, Vb, Bbuf, aplane, accB,
                                                  accA);
    ffn_kernel<<<4096, 256, 0, stream>>>(
        xr, xbuf, aplane, ln2_g + (size_t)d * CHW, ln2_b + (size_t)d * CHW,
        w1pk + d * 8192, b1 + d * 128, w2pk + d * 8192, b2 + d * 64, accB,
        accA);
    xr = xbuf;
  }
}

// Round 6
// 598.817 us; speedup vs baseline: 1.1021x; 1.1021x over previous
//
#include <hip/hip_runtime.h>

// Encoder: D=4, L=16, C=64, H=W=128.
// Math: softmax_j(A_i+B_j+ba)==softmax_j(B_j); attn identical for all i;
// B = conv5(h,Weff) as GEMM into 25 bf16 tap planes T + shift-add.
// R4: bucketed stat accumulators. R5: prep 64 blocks. R6: weight frags
// direct from global. R7: rotation LDS swizzle, wave acc-reduce, a-plane.
// R8: no x copy, bf16 T. R9 (this): R5's 64px experiment FALSIFIED the
// latency theory (occ 2x, time worse) -> pipeline runs at a ~2.2TB/s
// pattern ceiling; time == traffic/2.2TB/s. So: revert to 128px shapes
// (best measured), ffn caches x+a in LDS f32 (epilogue has NO global
// loads after GEMM2), attnc reworked to 8px/thread + ushort8 V loads +
// two-pass softmax (half the threads/requests, B reloaded from L2).

#define HW 16384
#define CHW 1048576
#define NB 64  // stat buckets; each bucket = 32 floats = one 128B line

typedef unsigned short u16;
typedef __attribute__((ext_vector_type(8))) short bf16x8;
typedef __attribute__((ext_vector_type(8))) unsigned short u16x8;
typedef __attribute__((ext_vector_type(4))) float f32x4;

static __device__ __forceinline__ u16 f2bf(float f) {
  union { float f; unsigned int u; } v; v.f = f;
  unsigned int r = v.u + 0x7fffu + ((v.u >> 16) & 1u);
  return (u16)(r >> 16);
}
static __device__ __forceinline__ float bf2f(u16 h) {
  union { unsigned int u; float f; } v; v.u = ((unsigned int)h) << 16;
  return v.f;
}
// LN stats from bucketed accumulators, wave-parallel: lane b loads bucket
// b's partial (one float2), butterfly-reduce across 64 lanes.
static __device__ __forceinline__ void ln_from_acc_wave(
    const float* acc, int l, int lane, float& mu, float& r) {
  const float invN = 1.f / 1048576.f;
  float2 v = *(const float2*)(acc + lane * 32 + 2 * l);
  float s = v.x, q = v.y;
#pragma unroll
  for (int off = 32; off > 0; off >>= 1) {
    s += __shfl_xor(s, off);
    q += __shfl_xor(q, off);
  }
  mu = s * invN;
  r = rsqrtf(q * invN - mu * mu + 1e-5f);
}

// ---- precompute bf16 MFMA fragment packs (layout identical for A/B use):
// pack[((t0*KT+kt)*64+lane)*8+j] = W[m=t0*16+(lane&15)][k=kt*32+(lane>>4)*8+j]
__global__ __launch_bounds__(256) void prep_kernel(
    const float* __restrict__ Wa, const float* __restrict__ Wk,
    const float* __restrict__ Wv, const float* __restrict__ W1,
    const float* __restrict__ W2, u16* __restrict__ w1pk,
    u16* __restrict__ w2pk, u16* __restrict__ wvpk, u16* __restrict__ wepk) {
  int d = blockIdx.x;
  int t = blockIdx.y * 256 + threadIdx.x;  // 0..4095
  const int STR = 256 * 16;
  const float* WaK = Wa + ((size_t)d * 128 + 64) * 25;
  const float* Wkd = Wk + d * 4096;
  for (int idx = t; idx < 2048; idx += STR) {  // Weff: m=tap(32), k=ci(64)
    int frag = idx >> 9, lane = (idx >> 3) & 63, j = idx & 7;
    int mt = frag >> 1, kt = frag & 1;
    int tap = mt * 16 + (lane & 15);
    int ci = kt * 32 + (lane >> 4) * 8 + j;
    float s = 0.f;
    if (tap < 25)
      for (int co = 0; co < 64; ++co)
        s = fmaf(WaK[co * 25 + tap], Wkd[co * 64 + ci], s);
    wepk[d * 2048 + idx] = f2bf(s);
  }
  const float* Wvd = Wv + d * 4096;
  for (int idx = t; idx < 4096; idx += STR) {  // Wv: m=co(64), k=ci(64)
    int frag = idx >> 9, lane = (idx >> 3) & 63, j = idx & 7;
    int mt = frag >> 1, kt = frag & 1;
    int co = mt * 16 + (lane & 15);
    int ci = kt * 32 + (lane >> 4) * 8 + j;
    wvpk[d * 4096 + idx] = f2bf(Wvd[co * 64 + ci]);
  }
  const float* W1d = W1 + d * 8192;
  for (int idx = t; idx < 8192; idx += STR) {  // W1: m=o(128), k=ci(64)
    int frag = idx >> 9, lane = (idx >> 3) & 63, j = idx & 7;
    int mt = frag >> 1, kt = frag & 1;
    int o = mt * 16 + (lane & 15);
    int ci = kt * 32 + (lane >> 4) * 8 + j;
    w1pk[d * 8192 + idx] = f2bf(W1d[o * 64 + ci]);
  }
  const float* W2d = W2 + d * 8192;
  for (int idx = t; idx < 8192; idx += STR) {  // W2: m=c(64), k=o(128)
    int frag = idx >> 9, lane = (idx >> 3) & 63, j = idx & 7;
    int mt2 = frag >> 2, kt2 = frag & 3;
    int c = mt2 * 16 + (lane & 15);
    int o = kt2 * 32 + (lane >> 4) * 8 + j;
    w2pk[d * 8192 + idx] = f2bf(W2d[c * 128 + o]);
  }
}

// ---- per-frame stats of x_in (bucketed); no copy ----
__global__ __launch_bounds__(256) void stats_kernel(
    const float* __restrict__ xin, float* __restrict__ acc) {
  int tid = threadIdx.x;
  size_t base = (size_t)blockIdx.x * 4096;
  const float4* in4 = (const float4*)(xin + base);
  float s = 0.f, q = 0.f;
#pragma unroll
  for (int k = 0; k < 4; ++k) {
    float4 v = in4[k * 256 + tid];
    s += v.x + v.y + v.z + v.w;
    q = fmaf(v.x, v.x, q); q = fmaf(v.y, v.y, q);
    q = fmaf(v.z, v.z, q); q = fmaf(v.w, v.w, q);
  }
#pragma unroll
  for (int off = 32; off > 0; off >>= 1) {
    s += __shfl_down(s, off); q += __shfl_down(q, off);
  }
  __shared__ float ls[4], lq[4];
  int wave = tid >> 6;
  if ((tid & 63) == 0) { ls[wave] = s; lq[wave] = q; }
  __syncthreads();
  if (tid == 0) {
    int frame = blockIdx.x >> 8;
    int bkt = blockIdx.x & (NB - 1);
    atomicAdd(&acc[bkt * 32 + frame * 2], ls[0] + ls[1] + ls[2] + ls[3]);
    atomicAdd(&acc[bkt * 32 + frame * 2 + 1], lq[0] + lq[1] + lq[2] + lq[3]);
  }
}

// ---- fused LN1 + V GEMM + T GEMM, 128 px/block (R4 shape) ----
// LDS: hb[128][72] u16 chunk-rotated (18432 B). Weights direct-global.
__global__ __launch_bounds__(256) void vb_kernel(
    const float* __restrict__ x, const float* __restrict__ g,
    const float* __restrict__ bln, const u16* __restrict__ wvp_g,
    const float* __restrict__ bv, const u16* __restrict__ wep_g,
    const float* __restrict__ accA, float* __restrict__ accBz,
    u16* __restrict__ Vb, u16* __restrict__ T) {
  __shared__ __align__(16) char lds[18432];
  u16* hb = (u16*)lds;
  int tid = threadIdx.x;
  int l = blockIdx.y;
  int p0 = blockIdx.x << 7;
  // zero accB buckets for attnc_update (safe: no other kernel concurrent)
  if (blockIdx.x == 0 && blockIdx.y == 0)
    for (int i = tid; i < NB * 32; i += 256) accBz[i] = 0.f;
  int lane = tid & 63;
  float mu, r;
  ln_from_acc_wave(accA, l, lane, mu, r);

  // stage h[px][ci] bf16 with chunk-rotated writes
#pragma unroll
  for (int it = 0; it < 2; ++it) {
    int pq = tid & 31, cg = (tid >> 5) + it * 8;
    int px = pq * 4, c0 = cg * 4;
    float vv[4][4];
#pragma unroll
    for (int i = 0; i < 4; ++i) {
      int c = c0 + i;
      size_t gi = (((size_t)l * 64 + c) << 14) + p0 + px;
      int li = (c << 14) + p0 + px;
      float4 xv = *(const float4*)(x + gi);
      float4 gv = *(const float4*)(g + li);
      float4 bb = *(const float4*)(bln + li);
      vv[i][0] = (xv.x - mu) * r * gv.x + bb.x;
      vv[i][1] = (xv.y - mu) * r * gv.y + bb.y;
      vv[i][2] = (xv.z - mu) * r * gv.z + bb.z;
      vv[i][3] = (xv.w - mu) * r * gv.w + bb.w;
    }
#pragma unroll
    for (int k = 0; k < 4; ++k) {
      int row = px + k;
      int col = ((((c0 >> 3) + (row >> 2)) & 7) << 3) | (c0 & 7);
      ushort4 hv;
      hv.x = f2bf(vv[0][k]); hv.y = f2bf(vv[1][k]);
      hv.z = f2bf(vv[2][k]); hv.w = f2bf(vv[3][k]);
      *(ushort4*)(hb + row * 72 + col) = hv;
    }
  }
  __syncthreads();

  int wv = tid >> 6;
  int ln15 = lane & 15, quad = lane >> 4;

  // A = h rows (m=px) from LDS (rotated chunks); B = weight frags global
  bf16x8 ah[2][2];
#pragma unroll
  for (int mt = 0; mt < 2; ++mt) {
    int px = (wv * 2 + mt) * 16 + ln15;
#pragma unroll
    for (int kt = 0; kt < 2; ++kt) {
      int slot = ((kt * 4 + quad) + (px >> 2)) & 7;
      ah[mt][kt] = *(const bf16x8*)(hb + px * 72 + (slot << 3));
    }
  }
  const bf16x8* wvg = (const bf16x8*)wvp_g;  // frag f at wvg[f*64+lane]
  const bf16x8* weg = (const bf16x8*)wep_g;

  f32x4 accV[2][4], accT[2][2];
#pragma unroll
  for (int mt = 0; mt < 2; ++mt) {
#pragma unroll
    for (int nt = 0; nt < 4; ++nt) accV[mt][nt] = (f32x4){0.f, 0.f, 0.f, 0.f};
#pragma unroll
    for (int nt = 0; nt < 2; ++nt) accT[mt][nt] = (f32x4){0.f, 0.f, 0.f, 0.f};
  }
#pragma unroll
  for (int nt = 0; nt < 4; ++nt) {
    bf16x8 b0 = wvg[(nt * 2 + 0) * 64 + lane];
    bf16x8 b1w = wvg[(nt * 2 + 1) * 64 + lane];
#pragma unroll
    for (int mt = 0; mt < 2; ++mt) {
      accV[mt][nt] = __builtin_amdgcn_mfma_f32_16x16x32_bf16(
          ah[mt][0], b0, accV[mt][nt], 0, 0, 0);
      accV[mt][nt] = __builtin_amdgcn_mfma_f32_16x16x32_bf16(
          ah[mt][1], b1w, accV[mt][nt], 0, 0, 0);
    }
  }
#pragma unroll
  for (int nt = 0; nt < 2; ++nt) {
    bf16x8 b0 = weg[(nt * 2 + 0) * 64 + lane];
    bf16x8 b1w = weg[(nt * 2 + 1) * 64 + lane];
#pragma unroll
    for (int mt = 0; mt < 2; ++mt) {
      accT[mt][nt] = __builtin_amdgcn_mfma_f32_16x16x32_bf16(
          ah[mt][0], b0, accT[mt][nt], 0, 0, 0);
      accT[mt][nt] = __builtin_amdgcn_mfma_f32_16x16x32_bf16(
          ah[mt][1], b1w, accT[mt][nt], 0, 0, 0);
    }
  }

  // epilogue: D rows = px (quad*4+rj) -> ushort4 stores (V and T bf16)
#pragma unroll
  for (int mt = 0; mt < 2; ++mt) {
    int pxb = p0 + (wv * 2 + mt) * 16 + quad * 4;
#pragma unroll
    for (int nt = 0; nt < 4; ++nt) {
      int c = nt * 16 + ln15;
      float bvc = bv[c];
      ushort4 o;
      o.x = f2bf(accV[mt][nt][0] + bvc);
      o.y = f2bf(accV[mt][nt][1] + bvc);
      o.z = f2bf(accV[mt][nt][2] + bvc);
      o.w = f2bf(accV[mt][nt][3] + bvc);
      *(ushort4*)(Vb + (((size_t)l * 64 + c) << 14) + pxb) = o;
    }
#pragma unroll
    for (int nt = 0; nt < 2; ++nt) {
      int tap = nt * 16 + ln15;
      if (tap < 25) {
        ushort4 o;
        o.x = f2bf(accT[mt][nt][0]); o.y = f2bf(accT[mt][nt][1]);
        o.z = f2bf(accT[mt][nt][2]); o.w = f2bf(accT[mt][nt][3]);
        *(ushort4*)(T + (((size_t)l * 25 + tap) << 14) + pxb) = o;
      }
    }
  }
}

// ---- B[l][p] = sum_tap T[l][tap][p + off(tap)] (T bf16) ----
__global__ __launch_bounds__(256) void bconv_kernel(
    const u16* __restrict__ T, float* __restrict__ B) {
  int gid = blockIdx.x * 256 + threadIdx.x;
  int l = gid >> 14, p = gid & 16383;
  int y = p >> 7, xx = p & 127;
  float s = 0.f;
#pragma unroll
  for (int dy = 0; dy < 5; ++dy) {
    int yy = y + dy - 2;
    if (yy < 0 || yy > 127) continue;
#pragma unroll
    for (int dx = 0; dx < 5; ++dx) {
      int xc = xx + dx - 2;
      if (xc < 0 || xc > 127) continue;
      s += bf2f(T[(((size_t)l * 25 + dy * 5 + dx) << 14) + (yy << 7) + xc]);
    }
  }
  B[gid] = s;
}

// ---- fused: softmax over j, attnc -> a-plane write + stats of (x+a) ----
// 8 px/thread, two-pass softmax (B 1MB, L2-hot reload), ushort8 V loads.
// grid 512x256.
__global__ __launch_bounds__(256) void attnc_update_kernel(
    const float* __restrict__ x, const u16* __restrict__ Vb,
    const float* __restrict__ B, float* __restrict__ ap,
    float* __restrict__ accB, float* __restrict__ accAz) {
  int tid = threadIdx.x;
  if (blockIdx.x == 0)  // zero accA buckets for ffn
    for (int i = tid; i < NB * 32; i += 256) accAz[i] = 0.f;
  int gid = blockIdx.x * 256 + tid;
  int c = gid >> 11;
  int p8 = (gid & 2047) << 3;
  // pass 1: per-px max over j
  float m[8];
#pragma unroll
  for (int k = 0; k < 8; ++k) m[k] = -1e30f;
#pragma unroll
  for (int j = 0; j < 16; ++j) {
    float4 b0 = *(const float4*)(B + (j << 14) + p8);
    float4 b1 = *(const float4*)(B + (j << 14) + p8 + 4);
    m[0] = fmaxf(m[0], b0.x); m[1] = fmaxf(m[1], b0.y);
    m[2] = fmaxf(m[2], b0.z); m[3] = fmaxf(m[3], b0.w);
    m[4] = fmaxf(m[4], b1.x); m[5] = fmaxf(m[5], b1.y);
    m[6] = fmaxf(m[6], b1.z); m[7] = fmaxf(m[7], b1.w);
  }
  // pass 2: exp-sum + V accumulate
  float sum[8], a[8];
#pragma unroll
  for (int k = 0; k < 8; ++k) { sum[k] = 0.f; a[k] = 0.f; }
#pragma unroll
  for (int j = 0; j < 16; ++j) {
    float4 b0 = *(const float4*)(B + (j << 14) + p8);
    float4 b1 = *(const float4*)(B + (j << 14) + p8 + 4);
    float e[8];
    e[0] = __expf(b0.x - m[0]); e[1] = __expf(b0.y - m[1]);
    e[2] = __expf(b0.z - m[2]); e[3] = __expf(b0.w - m[3]);
    e[4] = __expf(b1.x - m[4]); e[5] = __expf(b1.y - m[5]);
    e[6] = __expf(b1.z - m[6]); e[7] = __expf(b1.w - m[7]);
    u16x8 v = *(const u16x8*)(Vb + (((size_t)j * 64 + c) << 14) + p8);
#pragma unroll
    for (int k = 0; k < 8; ++k) {
      sum[k] += e[k];
      a[k] = fmaf(e[k], bf2f(v[k]), a[k]);
    }
  }
#pragma unroll
  for (int k = 0; k < 8; ++k) a[k] /= sum[k];
  float4 a0 = {a[0], a[1], a[2], a[3]};
  float4 a1 = {a[4], a[5], a[6], a[7]};
  *(float4*)(ap + ((size_t)c << 14) + p8) = a0;
  *(float4*)(ap + ((size_t)c << 14) + p8 + 4) = a1;
  // per-frame stats of (x + a), read-only x
  float sf[16], qf[16];
#pragma unroll
  for (int f = 0; f < 16; ++f) {
    size_t gi = ((size_t)f << 20) + ((size_t)c << 14) + p8;
    float4 v0 = *(const float4*)(x + gi);
    float4 v1 = *(const float4*)(x + gi + 4);
    v0.x += a0.x; v0.y += a0.y; v0.z += a0.z; v0.w += a0.w;
    v1.x += a1.x; v1.y += a1.y; v1.z += a1.z; v1.w += a1.w;
    sf[f] = v0.x + v0.y + v0.z + v0.w + v1.x + v1.y + v1.z + v1.w;
    float q = 0.f;
    q = fmaf(v0.x, v0.x, q); q = fmaf(v0.y, v0.y, q);
    q = fmaf(v0.z, v0.z, q); q = fmaf(v0.w, v0.w, q);
    q = fmaf(v1.x, v1.x, q); q = fmaf(v1.y, v1.y, q);
    q = fmaf(v1.z, v1.z, q); q = fmaf(v1.w, v1.w, q);
    qf[f] = q;
  }
#pragma unroll
  for (int off = 32; off > 0; off >>= 1) {
#pragma unroll
    for (int f = 0; f < 16; ++f) {
      sf[f] += __shfl_down(sf[f], off);
      qf[f] += __shfl_down(qf[f], off);
    }
  }
  __shared__ float lsq[4][32];
  int wv = tid >> 6;
  if ((tid & 63) == 0) {
#pragma unroll
    for (int f = 0; f < 16; ++f) {
      lsq[wv][2 * f] = sf[f];
      lsq[wv][2 * f + 1] = qf[f];
    }
  }
  __syncthreads();
  if (tid < 32) {
    int bkt = blockIdx.x & (NB - 1);
    atomicAdd(&accB[bkt * 32 + tid],
              lsq[0][tid] + lsq[1][tid] + lsq[2][tid] + lsq[3][tid]);
  }
}

// ---- fused attn-add + LN2 + FFN + residual + stats, 128 px/block ----
// h = LN(xr+a); xw = xr + a + W2*leaky(W1*h+b1) + b2.
// LDS: xa[64][132] f32 (33792) | hb[128][72] rotated (18432) overlaid by
// f1[128][128] swz (32768). Total 66560 B. Epilogue reads xa from LDS:
// no global loads after GEMM2.
__global__ __launch_bounds__(256) void ffn_kernel(
    const float* __restrict__ xr, float* __restrict__ xw,
    const float* __restrict__ ap, const float* __restrict__ g,
    const float* __restrict__ bln, const u16* __restrict__ w1p_g,
    const float* __restrict__ b1, const u16* __restrict__ w2p_g,
    const float* __restrict__ b2, const float* __restrict__ accB,
    float* __restrict__ accA) {
  __shared__ __align__(16) char lds[66560];
  float* xaf = (float*)lds;            // [64 c][132 px-padded] f32
  u16* hb = (u16*)(lds + 33792);       // [128][72] chunk-rotated
  u16* f1 = (u16*)(lds + 33792);       // [128][128] swz, overlays hb

  int tid = threadIdx.x;
  int P0 = blockIdx.x << 7;
  int l = P0 >> 14;
  int p0 = P0 & 16383;
  int lane = tid & 63;
  float mu, r;
  ln_from_acc_wave(accB, l, lane, mu, r);

  // stage: xa = x + a -> LDS f32; h = LN(xa) -> hb (chunk-rotated)
#pragma unroll
  for (int it = 0; it < 2; ++it) {
    int pq = tid & 31, cg = (tid >> 5) + it * 8;
    int px = pq * 4, c0 = cg * 4;
    float vv[4][4];
#pragma unroll
    for (int i = 0; i < 4; ++i) {
      int c = c0 + i;
      size_t gi = (((size_t)l * 64 + c) << 14) + p0 + px;
      int li = (c << 14) + p0 + px;
      float4 xv = *(const float4*)(xr + gi);
      float4 av = *(const float4*)(ap + li);
      float4 gv = *(const float4*)(g + li);
      float4 bb = *(const float4*)(bln + li);
      float4 s4;
      s4.x = xv.x + av.x; s4.y = xv.y + av.y;
      s4.z = xv.z + av.z; s4.w = xv.w + av.w;
      *(float4*)(xaf + c * 132 + px) = s4;
      vv[i][0] = (s4.x - mu) * r * gv.x + bb.x;
      vv[i][1] = (s4.y - mu) * r * gv.y + bb.y;
      vv[i][2] = (s4.z - mu) * r * gv.z + bb.z;
      vv[i][3] = (s4.w - mu) * r * gv.w + bb.w;
    }
#pragma unroll
    for (int k = 0; k < 4; ++k) {
      int row = px + k;
      int col = ((((c0 >> 3) + (row >> 2)) & 7) << 3) | (c0 & 7);
      ushort4 hv;
      hv.x = f2bf(vv[0][k]); hv.y = f2bf(vv[1][k]);
      hv.z = f2bf(vv[2][k]); hv.w = f2bf(vv[3][k]);
      *(ushort4*)(hb + row * 72 + col) = hv;
    }
  }
  __syncthreads();

  int wv = tid >> 6;
  int ln15 = lane & 15, quad = lane >> 4;

  // h fragments -> registers (rotated chunk reads)
  bf16x8 bh[2][2];
#pragma unroll
  for (int nt = 0; nt < 2; ++nt) {
    int px = (wv * 2 + nt) * 16 + ln15;
#pragma unroll
    for (int kt = 0; kt < 2; ++kt) {
      int slot = ((kt * 4 + quad) + (px >> 2)) & 7;
      bh[nt][kt] = *(const bf16x8*)(hb + px * 72 + (slot << 3));
    }
  }
  __syncthreads();  // all hb reads drained; f1 may now overwrite

  const bf16x8* w1g = (const bf16x8*)w1p_g;  // frag f at w1g[f*64+lane]
  const bf16x8* w2g = (const bf16x8*)w2p_g;

  // GEMM1 per o-tile mt: load 2 W1 frags, 4 MFMAs, bias+leaky, f1 write
#pragma unroll
  for (int mt = 0; mt < 8; ++mt) {
    bf16x8 a1a = w1g[(mt * 2 + 0) * 64 + lane];
    bf16x8 a1b = w1g[(mt * 2 + 1) * 64 + lane];
    f32x4 acc[2];
    acc[0] = (f32x4){0.f, 0.f, 0.f, 0.f};
    acc[1] = (f32x4){0.f, 0.f, 0.f, 0.f};
#pragma unroll
    for (int nt = 0; nt < 2; ++nt) {
      acc[nt] = __builtin_amdgcn_mfma_f32_16x16x32_bf16(a1a, bh[nt][0],
                                                        acc[nt], 0, 0, 0);
      acc[nt] = __builtin_amdgcn_mfma_f32_16x16x32_bf16(a1b, bh[nt][1],
                                                        acc[nt], 0, 0, 0);
    }
    int o0 = mt * 16 + quad * 4;
    float4 b1v = *(const float4*)(b1 + o0);
#pragma unroll
    for (int nt = 0; nt < 2; ++nt) {
      int px = (wv * 2 + nt) * 16 + ln15;
      int swz = (px & 7) * 8;
      float fv[4];
#pragma unroll
      for (int rj = 0; rj < 4; ++rj) {
        float f = acc[nt][rj] + ((const float*)&b1v)[rj];
        fv[rj] = fmaxf(f, 0.01f * f);
      }
      int col = ((o0 & ~7) ^ swz) + (o0 & 7);
      ushort4 ov;
      ov.x = f2bf(fv[0]); ov.y = f2bf(fv[1]);
      ov.z = f2bf(fv[2]); ov.w = f2bf(fv[3]);
      *(ushort4*)(f1 + px * 128 + col) = ov;
    }
  }
  __syncthreads();

  // GEMM2 transposed: D[px][c], A=f1 rows, B=W2 frags direct from global
  bf16x8 a2[2][4];
#pragma unroll
  for (int mt = 0; mt < 2; ++mt) {
    int px = (wv * 2 + mt) * 16 + ln15;
    int swz = (px & 7) * 8;
#pragma unroll
    for (int kt = 0; kt < 4; ++kt)
      a2[mt][kt] =
          *(const bf16x8*)(f1 + px * 128 + ((kt * 32 + quad * 8) ^ swz));
  }
  f32x4 acc2[2][4];
#pragma unroll
  for (int mt = 0; mt < 2; ++mt)
#pragma unroll
    for (int nt = 0; nt < 4; ++nt) acc2[mt][nt] = (f32x4){0.f, 0.f, 0.f, 0.f};
#pragma unroll
  for (int nt = 0; nt < 4; ++nt) {
    bf16x8 bw[4];
#pragma unroll
    for (int kt = 0; kt < 4; ++kt) bw[kt] = w2g[(nt * 4 + kt) * 64 + lane];
#pragma unroll
    for (int mt = 0; mt < 2; ++mt)
#pragma unroll
      for (int kt = 0; kt < 4; ++kt)
        acc2[mt][nt] = __builtin_amdgcn_mfma_f32_16x16x32_bf16(
            a2[mt][kt], bw[kt], acc2[mt][nt], 0, 0, 0);
  }

  // epilogue: v = xa(LDS) + ffn_out -> xw; no global loads; stats
  float s = 0.f, q = 0.f;
#pragma unroll
  for (int mt = 0; mt < 2; ++mt) {
    int pxl = (wv * 2 + mt) * 16 + quad * 4;
#pragma unroll
    for (int nt = 0; nt < 4; ++nt) {
      int c = nt * 16 + ln15;
      float b2c = b2[c];
      const float* xac = xaf + c * 132 + pxl;
      float4 v;
      v.x = xac[0] + acc2[mt][nt][0] + b2c;
      v.y = xac[1] + acc2[mt][nt][1] + b2c;
      v.z = xac[2] + acc2[mt][nt][2] + b2c;
      v.w = xac[3] + acc2[mt][nt][3] + b2c;
      *(float4*)(xw + (((size_t)l * 64 + c) << 14) + p0 + pxl) = v;
      s += v.x + v.y + v.z + v.w;
      q = fmaf(v.x, v.x, q); q = fmaf(v.y, v.y, q);
      q = fmaf(v.z, v.z, q); q = fmaf(v.w, v.w, q);
    }
  }
#pragma unroll
  for (int off = 32; off > 0; off >>= 1) {
    s += __shfl_down(s, off); q += __shfl_down(q, off);
  }
  if (lane == 0) {
    int bkt = blockIdx.x & (NB - 1);
    atomicAdd(&accA[bkt * 32 + l * 2], s);
    atomicAdd(&accA[bkt * 32 + l * 2 + 1], q);
  }
}

extern "C" void kernel_launch(void* const* d_in, const int* in_sizes, int n_in,
                              void* d_out, int out_size, void* d_ws,
                              size_t ws_size, hipStream_t stream) {
  const float* x_in = (const float*)d_in[0];
  const float* ln1_g = (const float*)d_in[1];
  const float* ln1_b = (const float*)d_in[2];
  const float* Wk = (const float*)d_in[5];
  const float* Wv = (const float*)d_in[7];
  const float* bv = (const float*)d_in[8];
  const float* Wa = (const float*)d_in[9];
  const float* ln2_g = (const float*)d_in[11];
  const float* ln2_b = (const float*)d_in[12];
  const float* W1 = (const float*)d_in[13];
  const float* b1 = (const float*)d_in[14];
  const float* W2 = (const float*)d_in[15];
  const float* b2 = (const float*)d_in[16];

  float* xbuf = (float*)d_out;
  char* wsb = (char*)d_ws;
  u16* Vb = (u16*)wsb;                       // 33,554,432 B
  u16* T = (u16*)(wsb + 33554432);           // 13,107,200 B (bf16 taps)
  float* aplane = (float*)(wsb + 46661632);  // 4,194,304 B
  float* Bbuf = (float*)(wsb + 50855936);    // 1,048,576 B
  u16* w1pk = (u16*)(wsb + 51904512);        // 65,536 B
  u16* w2pk = (u16*)(wsb + 51970048);        // 65,536 B
  u16* wvpk = (u16*)(wsb + 52035584);        // 32,768 B
  u16* wepk = (u16*)(wsb + 52068352);        // 16,384 B
  float* accA = (float*)(wsb + 52084736);    // 8,192 B
  float* accB = (float*)(wsb + 52092928);    // 8,192 B

  hipMemsetAsync(accA, 0, 16384, stream);  // accA + accB
  prep_kernel<<<dim3(4, 16), 256, 0, stream>>>(Wa, Wk, Wv, W1, W2, w1pk, w2pk,
                                               wvpk, wepk);
  stats_kernel<<<4096, 256, 0, stream>>>(x_in, accA);

  const float* xr = x_in;
  for (int d = 0; d < 4; ++d) {
    vb_kernel<<<dim3(128, 16), 256, 0, stream>>>(
        xr, ln1_g + (size_t)d * CHW, ln1_b + (size_t)d * CHW, wvpk + d * 4096,
        bv + d * 64, wepk + d * 2048, accA, accB, Vb, T);
    bconv_kernel<<<1024, 256, 0, stream>>>(T, Bbuf);
    attnc_update_kernel<<<512, 256, 0, stream>>>(xr, Vb, Bbuf, aplane, accB,
                                                 accA);
    ffn_kernel<<<2048, 256, 0, stream>>>(
        xr, xbuf, aplane, ln2_g + (size_t)d * CHW, ln2_b + (size_t)d * CHW,
        w1pk + d * 8192, b1 + d * 128, w2pk + d * 8192, b2 + d * 64, accB,
        accA);
    xr = xbuf;
  }
}

// Round 7
// 565.250 us; speedup vs baseline: 1.1675x; 1.0594x over previous
//
#include <hip/hip_runtime.h>

// Encoder: D=4, L=16, C=64, H=W=128.
// Math: softmax_j(A_i+B_j+ba)==softmax_j(B_j); attn identical for all i;
// B = conv5(h,Weff) as GEMM into 25 bf16 tap planes T + shift-add.
// R7: rotation LDS swizzle, wave acc-reduce. R8: no x copy, bf16 T.
// R9: xa in LDS, 8px attnc. R10 (this): measured law dur~traffic/2.3TB/s
// -> eliminate V entirely via a = Wv*(g1*(sum_j P_j r_j x_j - scal)+b1)+bv
// (P frame-indep, V linear in h). vb -> tb (LN1 + T GEMM only, -32MB wr);
// attnc builds hbar from its existing x read, does the Wv GEMM per 64px
// tile (-32MB rd), writes bf16 a (-6MB); ln g/b converted to bf16 once
// (-12MB/depth). ~290MB/depth vs 372.

#define HW 16384
#define CHW 1048576
#define NB 64  // stat buckets; each bucket = 32 floats = one 128B line

typedef unsigned short u16;
typedef __attribute__((ext_vector_type(8))) short bf16x8;
typedef __attribute__((ext_vector_type(8))) unsigned short u16x8;
typedef __attribute__((ext_vector_type(4))) float f32x4;

static __device__ __forceinline__ u16 f2bf(float f) {
  union { float f; unsigned int u; } v; v.f = f;
  unsigned int r = v.u + 0x7fffu + ((v.u >> 16) & 1u);
  return (u16)(r >> 16);
}
static __device__ __forceinline__ float bf2f(u16 h) {
  union { unsigned int u; float f; } v; v.u = ((unsigned int)h) << 16;
  return v.f;
}
// LN stats from bucketed accumulators, wave-parallel.
static __device__ __forceinline__ void ln_from_acc_wave(
    const float* acc, int l, int lane, float& mu, float& r) {
  const float invN = 1.f / 1048576.f;
  float2 v = *(const float2*)(acc + lane * 32 + 2 * l);
  float s = v.x, q = v.y;
#pragma unroll
  for (int off = 32; off > 0; off >>= 1) {
    s += __shfl_xor(s, off);
    q += __shfl_xor(q, off);
  }
  mu = s * invN;
  r = rsqrtf(q * invN - mu * mu + 1e-5f);
}

// ---- precompute bf16 MFMA fragment packs ----
__global__ __launch_bounds__(256) void prep_kernel(
    const float* __restrict__ Wa, const float* __restrict__ Wk,
    const float* __restrict__ Wv, const float* __restrict__ W1,
    const float* __restrict__ W2, u16* __restrict__ w1pk,
    u16* __restrict__ w2pk, u16* __restrict__ wvpk, u16* __restrict__ wepk) {
  int d = blockIdx.x;
  int t = blockIdx.y * 256 + threadIdx.x;  // 0..4095
  const int STR = 256 * 16;
  const float* WaK = Wa + ((size_t)d * 128 + 64) * 25;
  const float* Wkd = Wk + d * 4096;
  for (int idx = t; idx < 2048; idx += STR) {  // Weff: m=tap(32), k=ci(64)
    int frag = idx >> 9, lane = (idx >> 3) & 63, j = idx & 7;
    int mt = frag >> 1, kt = frag & 1;
    int tap = mt * 16 + (lane & 15);
    int ci = kt * 32 + (lane >> 4) * 8 + j;
    float s = 0.f;
    if (tap < 25)
      for (int co = 0; co < 64; ++co)
        s = fmaf(WaK[co * 25 + tap], Wkd[co * 64 + ci], s);
    wepk[d * 2048 + idx] = f2bf(s);
  }
  const float* Wvd = Wv + d * 4096;
  for (int idx = t; idx < 4096; idx += STR) {  // Wv: m=co(64), k=ci(64)
    int frag = idx >> 9, lane = (idx >> 3) & 63, j = idx & 7;
    int mt = frag >> 1, kt = frag & 1;
    int co = mt * 16 + (lane & 15);
    int ci = kt * 32 + (lane >> 4) * 8 + j;
    wvpk[d * 4096 + idx] = f2bf(Wvd[co * 64 + ci]);
  }
  const float* W1d = W1 + d * 8192;
  for (int idx = t; idx < 8192; idx += STR) {  // W1: m=o(128), k=ci(64)
    int frag = idx >> 9, lane = (idx >> 3) & 63, j = idx & 7;
    int mt = frag >> 1, kt = frag & 1;
    int o = mt * 16 + (lane & 15);
    int ci = kt * 32 + (lane >> 4) * 8 + j;
    w1pk[d * 8192 + idx] = f2bf(W1d[o * 64 + ci]);
  }
  const float* W2d = W2 + d * 8192;
  for (int idx = t; idx < 8192; idx += STR) {  // W2: m=c(64), k=o(128)
    int frag = idx >> 9, lane = (idx >> 3) & 63, j = idx & 7;
    int mt2 = frag >> 2, kt2 = frag & 3;
    int c = mt2 * 16 + (lane & 15);
    int o = kt2 * 32 + (lane >> 4) * 8 + j;
    w2pk[d * 8192 + idx] = f2bf(W2d[c * 128 + o]);
  }
}

// ---- convert LN gamma/beta tensors to bf16 (one-time) ----
__global__ __launch_bounds__(256) void lngb_kernel(
    const float* __restrict__ g1, const float* __restrict__ b1,
    const float* __restrict__ g2, const float* __restrict__ b2,
    u16* __restrict__ o1, u16* __restrict__ o2, u16* __restrict__ o3,
    u16* __restrict__ o4) {
  int idx = blockIdx.x * 256 + threadIdx.x;  // 0..1048575 (x4 elems)
  const float* src;
  u16* dst;
  switch (blockIdx.y) {
    case 0: src = g1; dst = o1; break;
    case 1: src = b1; dst = o2; break;
    case 2: src = g2; dst = o3; break;
    default: src = b2; dst = o4; break;
  }
  float4 v = *(const float4*)(src + (size_t)idx * 4);
  ushort4 o;
  o.x = f2bf(v.x); o.y = f2bf(v.y); o.z = f2bf(v.z); o.w = f2bf(v.w);
  *(ushort4*)(dst + (size_t)idx * 4) = o;
}

// ---- per-frame stats of x_in (bucketed); no copy ----
__global__ __launch_bounds__(256) void stats_kernel(
    const float* __restrict__ xin, float* __restrict__ acc) {
  int tid = threadIdx.x;
  size_t base = (size_t)blockIdx.x * 4096;
  const float4* in4 = (const float4*)(xin + base);
  float s = 0.f, q = 0.f;
#pragma unroll
  for (int k = 0; k < 4; ++k) {
    float4 v = in4[k * 256 + tid];
    s += v.x + v.y + v.z + v.w;
    q = fmaf(v.x, v.x, q); q = fmaf(v.y, v.y, q);
    q = fmaf(v.z, v.z, q); q = fmaf(v.w, v.w, q);
  }
#pragma unroll
  for (int off = 32; off > 0; off >>= 1) {
    s += __shfl_down(s, off); q += __shfl_down(q, off);
  }
  __shared__ float ls[4], lq[4];
  int wave = tid >> 6;
  if ((tid & 63) == 0) { ls[wave] = s; lq[wave] = q; }
  __syncthreads();
  if (tid == 0) {
    int frame = blockIdx.x >> 8;
    int bkt = blockIdx.x & (NB - 1);
    atomicAdd(&acc[bkt * 32 + frame * 2], ls[0] + ls[1] + ls[2] + ls[3]);
    atomicAdd(&acc[bkt * 32 + frame * 2 + 1], lq[0] + lq[1] + lq[2] + lq[3]);
  }
}

// ---- LN1 + T GEMM only (V eliminated), 128 px/block ----
// LDS: hb[128][72] u16 chunk-rotated (18432 B).
__global__ __launch_bounds__(256) void tb_kernel(
    const float* __restrict__ x, const u16* __restrict__ g,
    const u16* __restrict__ bln, const u16* __restrict__ wep_g,
    const float* __restrict__ accA, float* __restrict__ accBz,
    float* __restrict__ mulr, u16* __restrict__ T) {
  __shared__ __align__(16) char lds[18432];
  u16* hb = (u16*)lds;
  int tid = threadIdx.x;
  int l = blockIdx.y;
  int p0 = blockIdx.x << 7;
  if (blockIdx.x == 0 && blockIdx.y == 0)
    for (int i = tid; i < NB * 32; i += 256) accBz[i] = 0.f;
  int lane = tid & 63;
  float mu, r;
  ln_from_acc_wave(accA, l, lane, mu, r);
  if (blockIdx.x == 0 && tid == 0) {
    mulr[2 * l] = mu;
    mulr[2 * l + 1] = r;
  }

  // stage h[px][ci] bf16 with chunk-rotated writes (g/bln bf16)
#pragma unroll
  for (int it = 0; it < 2; ++it) {
    int pq = tid & 31, cg = (tid >> 5) + it * 8;
    int px = pq * 4, c0 = cg * 4;
    float vv[4][4];
#pragma unroll
    for (int i = 0; i < 4; ++i) {
      int c = c0 + i;
      size_t gi = (((size_t)l * 64 + c) << 14) + p0 + px;
      int li = (c << 14) + p0 + px;
      float4 xv = *(const float4*)(x + gi);
      ushort4 gv = *(const ushort4*)(g + li);
      ushort4 bb = *(const ushort4*)(bln + li);
      vv[i][0] = (xv.x - mu) * r * bf2f(gv.x) + bf2f(bb.x);
      vv[i][1] = (xv.y - mu) * r * bf2f(gv.y) + bf2f(bb.y);
      vv[i][2] = (xv.z - mu) * r * bf2f(gv.z) + bf2f(bb.z);
      vv[i][3] = (xv.w - mu) * r * bf2f(gv.w) + bf2f(bb.w);
    }
#pragma unroll
    for (int k = 0; k < 4; ++k) {
      int row = px + k;
      int col = ((((c0 >> 3) + (row >> 2)) & 7) << 3) | (c0 & 7);
      ushort4 hv;
      hv.x = f2bf(vv[0][k]); hv.y = f2bf(vv[1][k]);
      hv.z = f2bf(vv[2][k]); hv.w = f2bf(vv[3][k]);
      *(ushort4*)(hb + row * 72 + col) = hv;
    }
  }
  __syncthreads();

  int wv = tid >> 6;
  int ln15 = lane & 15, quad = lane >> 4;

  bf16x8 ah[2][2];
#pragma unroll
  for (int mt = 0; mt < 2; ++mt) {
    int px = (wv * 2 + mt) * 16 + ln15;
#pragma unroll
    for (int kt = 0; kt < 2; ++kt) {
      int slot = ((kt * 4 + quad) + (px >> 2)) & 7;
      ah[mt][kt] = *(const bf16x8*)(hb + px * 72 + (slot << 3));
    }
  }
  const bf16x8* weg = (const bf16x8*)wep_g;

  f32x4 accT[2][2];
#pragma unroll
  for (int mt = 0; mt < 2; ++mt)
#pragma unroll
    for (int nt = 0; nt < 2; ++nt) accT[mt][nt] = (f32x4){0.f, 0.f, 0.f, 0.f};
#pragma unroll
  for (int nt = 0; nt < 2; ++nt) {
    bf16x8 b0 = weg[(nt * 2 + 0) * 64 + lane];
    bf16x8 b1w = weg[(nt * 2 + 1) * 64 + lane];
#pragma unroll
    for (int mt = 0; mt < 2; ++mt) {
      accT[mt][nt] = __builtin_amdgcn_mfma_f32_16x16x32_bf16(
          ah[mt][0], b0, accT[mt][nt], 0, 0, 0);
      accT[mt][nt] = __builtin_amdgcn_mfma_f32_16x16x32_bf16(
          ah[mt][1], b1w, accT[mt][nt], 0, 0, 0);
    }
  }

#pragma unroll
  for (int mt = 0; mt < 2; ++mt) {
    int pxb = p0 + (wv * 2 + mt) * 16 + quad * 4;
#pragma unroll
    for (int nt = 0; nt < 2; ++nt) {
      int tap = nt * 16 + ln15;
      if (tap < 25) {
        ushort4 o;
        o.x = f2bf(accT[mt][nt][0]); o.y = f2bf(accT[mt][nt][1]);
        o.z = f2bf(accT[mt][nt][2]); o.w = f2bf(accT[mt][nt][3]);
        *(ushort4*)(T + (((size_t)l * 25 + tap) << 14) + pxb) = o;
      }
    }
  }
}

// ---- B[l][p] = sum_tap T[l][tap][p + off(tap)] (T bf16) ----
__global__ __launch_bounds__(256) void bconv_kernel(
    const u16* __restrict__ T, float* __restrict__ B) {
  int gid = blockIdx.x * 256 + threadIdx.x;
  int l = gid >> 14, p = gid & 16383;
  int y = p >> 7, xx = p & 127;
  float s = 0.f;
#pragma unroll
  for (int dy = 0; dy < 5; ++dy) {
    int yy = y + dy - 2;
    if (yy < 0 || yy > 127) continue;
#pragma unroll
    for (int dx = 0; dx < 5; ++dx) {
      int xc = xx + dx - 2;
      if (xc < 0 || xc > 127) continue;
      s += bf2f(T[(((size_t)l * 25 + dy * 5 + dx) << 14) + (yy << 7) + xc]);
    }
  }
  B[gid] = s;
}

// ---- fused softmax + hbar + Wv-GEMM -> a (bf16) + stats of (x+a) ----
// a = Wv*(g1*(sum_j P_j r_j x_j - scal) + b1) + bv. 64px tile/block,
// grid 256. V tensor never materialized.
__global__ __launch_bounds__(256) void attnc_kernel(
    const float* __restrict__ x, const float* __restrict__ B,
    const u16* __restrict__ g1, const u16* __restrict__ b1g,
    const u16* __restrict__ wvp_g, const float* __restrict__ bv,
    const float* __restrict__ mulr, u16* __restrict__ abf,
    float* __restrict__ accB, float* __restrict__ accAz) {
  __shared__ float Prl[16][64];
  __shared__ float scal[64];
  __shared__ __align__(16) u16 hb[64 * 72];
  __shared__ float lsq[4][32];
  int tid = threadIdx.x;
  int p0 = blockIdx.x << 6;
  if (blockIdx.x == 0)  // zero accA buckets for ffn
    for (int i = tid; i < NB * 32; i += 256) accAz[i] = 0.f;

  // phase A: softmax weights (threads 0..63 own one px each)
  if (tid < 64) {
    float bj[16], m = -1e30f;
#pragma unroll
    for (int j = 0; j < 16; ++j) {
      bj[j] = B[(j << 14) + p0 + tid];
      m = fmaxf(m, bj[j]);
    }
    float sum = 0.f;
#pragma unroll
    for (int j = 0; j < 16; ++j) {
      bj[j] = __expf(bj[j] - m);
      sum += bj[j];
    }
    float inv = 1.f / sum;
    float sc = 0.f;
#pragma unroll
    for (int j = 0; j < 16; ++j) {
      float mu_j = mulr[2 * j], r_j = mulr[2 * j + 1];
      float prl = bj[j] * inv * r_j;
      Prl[j][tid] = prl;
      sc = fmaf(prl, mu_j, sc);
    }
    scal[tid] = sc;
  }
  __syncthreads();

  // phase B: xbar = sum_j Prl[j]*x_j ; hbar = g1*(xbar-scal)+b1 -> hb
  int csub = tid >> 4, pxq = tid & 15;  // wave: 4 c-rows x 16 px-quads
  f32x4 xbar[4];
#pragma unroll
  for (int cc = 0; cc < 4; ++cc) xbar[cc] = (f32x4){0.f, 0.f, 0.f, 0.f};
#pragma unroll
  for (int j = 0; j < 16; ++j) {
    f32x4 P4 = *(const f32x4*)&Prl[j][pxq * 4];
#pragma unroll
    for (int cc = 0; cc < 4; ++cc) {
      int c = cc * 16 + csub;
      float4 xv =
          *(const float4*)(x + (((size_t)j * 64 + c) << 14) + p0 + pxq * 4);
      xbar[cc][0] = fmaf(P4[0], xv.x, xbar[cc][0]);
      xbar[cc][1] = fmaf(P4[1], xv.y, xbar[cc][1]);
      xbar[cc][2] = fmaf(P4[2], xv.z, xbar[cc][2]);
      xbar[cc][3] = fmaf(P4[3], xv.w, xbar[cc][3]);
    }
  }
  {
    f32x4 sc4 = *(const f32x4*)&scal[pxq * 4];
#pragma unroll
    for (int cc = 0; cc < 4; ++cc) {
      int c = cc * 16 + csub;
      ushort4 g4 = *(const ushort4*)(g1 + ((size_t)c << 14) + p0 + pxq * 4);
      ushort4 b4 = *(const ushort4*)(b1g + ((size_t)c << 14) + p0 + pxq * 4);
      float hv[4];
      hv[0] = bf2f(g4.x) * (xbar[cc][0] - sc4[0]) + bf2f(b4.x);
      hv[1] = bf2f(g4.y) * (xbar[cc][1] - sc4[1]) + bf2f(b4.y);
      hv[2] = bf2f(g4.z) * (xbar[cc][2] - sc4[2]) + bf2f(b4.z);
      hv[3] = bf2f(g4.w) * (xbar[cc][3] - sc4[3]) + bf2f(b4.w);
#pragma unroll
      for (int k = 0; k < 4; ++k) {
        int row = pxq * 4 + k;
        int col = ((((c >> 3) + (row >> 2)) & 7) << 3) | (c & 7);
        hb[row * 72 + col] = f2bf(hv[k]);
      }
    }
  }
  __syncthreads();

  // phase C: a = Wv*hbar + bv (MFMA); wave owns 16 px
  int wv = tid >> 6, lane = tid & 63;
  int ln15 = lane & 15, quad = lane >> 4;
  int px = wv * 16 + ln15;
  bf16x8 ah[2];
#pragma unroll
  for (int kt = 0; kt < 2; ++kt) {
    int slot = ((kt * 4 + quad) + (px >> 2)) & 7;
    ah[kt] = *(const bf16x8*)(hb + px * 72 + (slot << 3));
  }
  const bf16x8* wvg = (const bf16x8*)wvp_g;
  f32x4 accV[4];
#pragma unroll
  for (int nt = 0; nt < 4; ++nt) accV[nt] = (f32x4){0.f, 0.f, 0.f, 0.f};
#pragma unroll
  for (int nt = 0; nt < 4; ++nt) {
    bf16x8 b0 = wvg[(nt * 2 + 0) * 64 + lane];
    bf16x8 b1w = wvg[(nt * 2 + 1) * 64 + lane];
    accV[nt] = __builtin_amdgcn_mfma_f32_16x16x32_bf16(ah[0], b0, accV[nt],
                                                       0, 0, 0);
    accV[nt] = __builtin_amdgcn_mfma_f32_16x16x32_bf16(ah[1], b1w, accV[nt],
                                                       0, 0, 0);
  }
  int pxb = p0 + wv * 16 + quad * 4;
  float av[4][4];
#pragma unroll
  for (int nt = 0; nt < 4; ++nt) {
    int c = nt * 16 + ln15;
    float bvc = bv[c];
    ushort4 o;
    av[nt][0] = accV[nt][0] + bvc; o.x = f2bf(av[nt][0]);
    av[nt][1] = accV[nt][1] + bvc; o.y = f2bf(av[nt][1]);
    av[nt][2] = accV[nt][2] + bvc; o.z = f2bf(av[nt][2]);
    av[nt][3] = accV[nt][3] + bvc; o.w = f2bf(av[nt][3]);
    *(ushort4*)(abf + ((size_t)c << 14) + pxb) = o;
  }

  // phase D: per-frame stats of (x + a); x re-read L2-hot
  float sf[16], qf[16];
#pragma unroll
  for (int f = 0; f < 16; ++f) {
    float s = 0.f, q = 0.f;
#pragma unroll
    for (int nt = 0; nt < 4; ++nt) {
      int c = nt * 16 + ln15;
      float4 xv =
          *(const float4*)(x + ((size_t)f << 20) + ((size_t)c << 14) + pxb);
      float v0 = xv.x + av[nt][0], v1 = xv.y + av[nt][1];
      float v2 = xv.z + av[nt][2], v3 = xv.w + av[nt][3];
      s += v0 + v1 + v2 + v3;
      q = fmaf(v0, v0, q); q = fmaf(v1, v1, q);
      q = fmaf(v2, v2, q); q = fmaf(v3, v3, q);
    }
    sf[f] = s; qf[f] = q;
  }
#pragma unroll
  for (int off = 32; off > 0; off >>= 1) {
#pragma unroll
    for (int f = 0; f < 16; ++f) {
      sf[f] += __shfl_down(sf[f], off);
      qf[f] += __shfl_down(qf[f], off);
    }
  }
  if (lane == 0) {
#pragma unroll
    for (int f = 0; f < 16; ++f) {
      lsq[wv][2 * f] = sf[f];
      lsq[wv][2 * f + 1] = qf[f];
    }
  }
  __syncthreads();
  if (tid < 32) {
    int bkt = blockIdx.x & (NB - 1);
    atomicAdd(&accB[bkt * 32 + tid],
              lsq[0][tid] + lsq[1][tid] + lsq[2][tid] + lsq[3][tid]);
  }
}

// ---- fused attn-add + LN2 + FFN + residual + stats, 128 px/block ----
// LDS: xa[64][132] f32 (33792) | hb[128][72] rot (18432) / f1 overlays.
__global__ __launch_bounds__(256) void ffn_kernel(
    const float* __restrict__ xr, float* __restrict__ xw,
    const u16* __restrict__ ap, const u16* __restrict__ g,
    const u16* __restrict__ bln, const u16* __restrict__ w1p_g,
    const float* __restrict__ b1, const u16* __restrict__ w2p_g,
    const float* __restrict__ b2, const float* __restrict__ accB,
    float* __restrict__ accA) {
  __shared__ __align__(16) char lds[66560];
  float* xaf = (float*)lds;       // [64 c][132 px-padded] f32
  u16* hb = (u16*)(lds + 33792);  // [128][72] chunk-rotated
  u16* f1 = (u16*)(lds + 33792);  // [128][128] swz, overlays hb

  int tid = threadIdx.x;
  int P0 = blockIdx.x << 7;
  int l = P0 >> 14;
  int p0 = P0 & 16383;
  int lane = tid & 63;
  float mu, r;
  ln_from_acc_wave(accB, l, lane, mu, r);

  // stage: xa = x + a -> LDS f32; h = LN(xa) -> hb (chunk-rotated)
#pragma unroll
  for (int it = 0; it < 2; ++it) {
    int pq = tid & 31, cg = (tid >> 5) + it * 8;
    int px = pq * 4, c0 = cg * 4;
    float vv[4][4];
#pragma unroll
    for (int i = 0; i < 4; ++i) {
      int c = c0 + i;
      size_t gi = (((size_t)l * 64 + c) << 14) + p0 + px;
      int li = (c << 14) + p0 + px;
      float4 xv = *(const float4*)(xr + gi);
      ushort4 av4 = *(const ushort4*)(ap + li);
      ushort4 gv = *(const ushort4*)(g + li);
      ushort4 bb = *(const ushort4*)(bln + li);
      float4 s4;
      s4.x = xv.x + bf2f(av4.x); s4.y = xv.y + bf2f(av4.y);
      s4.z = xv.z + bf2f(av4.z); s4.w = xv.w + bf2f(av4.w);
      *(float4*)(xaf + c * 132 + px) = s4;
      vv[i][0] = (s4.x - mu) * r * bf2f(gv.x) + bf2f(bb.x);
      vv[i][1] = (s4.y - mu) * r * bf2f(gv.y) + bf2f(bb.y);
      vv[i][2] = (s4.z - mu) * r * bf2f(gv.z) + bf2f(bb.z);
      vv[i][3] = (s4.w - mu) * r * bf2f(gv.w) + bf2f(bb.w);
    }
#pragma unroll
    for (int k = 0; k < 4; ++k) {
      int row = px + k;
      int col = ((((c0 >> 3) + (row >> 2)) & 7) << 3) | (c0 & 7);
      ushort4 hv;
      hv.x = f2bf(vv[0][k]); hv.y = f2bf(vv[1][k]);
      hv.z = f2bf(vv[2][k]); hv.w = f2bf(vv[3][k]);
      *(ushort4*)(hb + row * 72 + col) = hv;
    }
  }
  __syncthreads();

  int wv = tid >> 6;
  int ln15 = lane & 15, quad = lane >> 4;

  bf16x8 bh[2][2];
#pragma unroll
  for (int nt = 0; nt < 2; ++nt) {
    int px = (wv * 2 + nt) * 16 + ln15;
#pragma unroll
    for (int kt = 0; kt < 2; ++kt) {
      int slot = ((kt * 4 + quad) + (px >> 2)) & 7;
      bh[nt][kt] = *(const bf16x8*)(hb + px * 72 + (slot << 3));
    }
  }
  __syncthreads();  // all hb reads drained; f1 may now overwrite

  const bf16x8* w1g = (const bf16x8*)w1p_g;
  const bf16x8* w2g = (const bf16x8*)w2p_g;

  // GEMM1 per o-tile mt
#pragma unroll
  for (int mt = 0; mt < 8; ++mt) {
    bf16x8 a1a = w1g[(mt * 2 + 0) * 64 + lane];
    bf16x8 a1b = w1g[(mt * 2 + 1) * 64 + lane];
    f32x4 acc[2];
    acc[0] = (f32x4){0.f, 0.f, 0.f, 0.f};
    acc[1] = (f32x4){0.f, 0.f, 0.f, 0.f};
#pragma unroll
    for (int nt = 0; nt < 2; ++nt) {
      acc[nt] = __builtin_amdgcn_mfma_f32_16x16x32_bf16(a1a, bh[nt][0],
                                                        acc[nt], 0, 0, 0);
      acc[nt] = __builtin_amdgcn_mfma_f32_16x16x32_bf16(a1b, bh[nt][1],
                                                        acc[nt], 0, 0, 0);
    }
    int o0 = mt * 16 + quad * 4;
    float4 b1v = *(const float4*)(b1 + o0);
#pragma unroll
    for (int nt = 0; nt < 2; ++nt) {
      int px = (wv * 2 + nt) * 16 + ln15;
      int swz = (px & 7) * 8;
      float fv[4];
#pragma unroll
      for (int rj = 0; rj < 4; ++rj) {
        float f = acc[nt][rj] + ((const float*)&b1v)[rj];
        fv[rj] = fmaxf(f, 0.01f * f);
      }
      int col = ((o0 & ~7) ^ swz) + (o0 & 7);
      ushort4 ov;
      ov.x = f2bf(fv[0]); ov.y = f2bf(fv[1]);
      ov.z = f2bf(fv[2]); ov.w = f2bf(fv[3]);
      *(ushort4*)(f1 + px * 128 + col) = ov;
    }
  }
  __syncthreads();

  // GEMM2 transposed
  bf16x8 a2[2][4];
#pragma unroll
  for (int mt = 0; mt < 2; ++mt) {
    int px = (wv * 2 + mt) * 16 + ln15;
    int swz = (px & 7) * 8;
#pragma unroll
    for (int kt = 0; kt < 4; ++kt)
      a2[mt][kt] =
          *(const bf16x8*)(f1 + px * 128 + ((kt * 32 + quad * 8) ^ swz));
  }
  f32x4 acc2[2][4];
#pragma unroll
  for (int mt = 0; mt < 2; ++mt)
#pragma unroll
    for (int nt = 0; nt < 4; ++nt) acc2[mt][nt] = (f32x4){0.f, 0.f, 0.f, 0.f};
#pragma unroll
  for (int nt = 0; nt < 4; ++nt) {
    bf16x8 bw[4];
#pragma unroll
    for (int kt = 0; kt < 4; ++kt) bw[kt] = w2g[(nt * 4 + kt) * 64 + lane];
#pragma unroll
    for (int mt = 0; mt < 2; ++mt)
#pragma unroll
      for (int kt = 0; kt < 4; ++kt)
        acc2[mt][nt] = __builtin_amdgcn_mfma_f32_16x16x32_bf16(
            a2[mt][kt], bw[kt], acc2[mt][nt], 0, 0, 0);
  }

  // epilogue: v = xa(LDS) + ffn_out -> xw; stats
  float s = 0.f, q = 0.f;
#pragma unroll
  for (int mt = 0; mt < 2; ++mt) {
    int pxl = (wv * 2 + mt) * 16 + quad * 4;
#pragma unroll
    for (int nt = 0; nt < 4; ++nt) {
      int c = nt * 16 + ln15;
      float b2c = b2[c];
      const float* xac = xaf + c * 132 + pxl;
      float4 v;
      v.x = xac[0] + acc2[mt][nt][0] + b2c;
      v.y = xac[1] + acc2[mt][nt][1] + b2c;
      v.z = xac[2] + acc2[mt][nt][2] + b2c;
      v.w = xac[3] + acc2[mt][nt][3] + b2c;
      *(float4*)(xw + (((size_t)l * 64 + c) << 14) + p0 + pxl) = v;
      s += v.x + v.y + v.z + v.w;
      q = fmaf(v.x, v.x, q); q = fmaf(v.y, v.y, q);
      q = fmaf(v.z, v.z, q); q = fmaf(v.w, v.w, q);
    }
  }
#pragma unroll
  for (int off = 32; off > 0; off >>= 1) {
    s += __shfl_down(s, off); q += __shfl_down(q, off);
  }
  if (lane == 0) {
    int bkt = blockIdx.x & (NB - 1);
    atomicAdd(&accA[bkt * 32 + l * 2], s);
    atomicAdd(&accA[bkt * 32 + l * 2 + 1], q);
  }
}

extern "C" void kernel_launch(void* const* d_in, const int* in_sizes, int n_in,
                              void* d_out, int out_size, void* d_ws,
                              size_t ws_size, hipStream_t stream) {
  const float* x_in = (const float*)d_in[0];
  const float* ln1_g = (const float*)d_in[1];
  const float* ln1_b = (const float*)d_in[2];
  const float* Wk = (const float*)d_in[5];
  const float* Wv = (const float*)d_in[7];
  const float* bv = (const float*)d_in[8];
  const float* Wa = (const float*)d_in[9];
  const float* ln2_g = (const float*)d_in[11];
  const float* ln2_b = (const float*)d_in[12];
  const float* W1 = (const float*)d_in[13];
  const float* b1 = (const float*)d_in[14];
  const float* W2 = (const float*)d_in[15];
  const float* b2 = (const float*)d_in[16];

  float* xbuf = (float*)d_out;
  char* wsb = (char*)d_ws;
  u16* T = (u16*)wsb;                       // 13,107,200 B
  u16* abf = (u16*)(wsb + 13107200);        // 2,097,152 B
  float* Bbuf = (float*)(wsb + 15204352);   // 1,048,576 B
  u16* g1b = (u16*)(wsb + 16252928);        // 8,388,608 B
  u16* b1bb = (u16*)(wsb + 24641536);       // 8,388,608 B
  u16* g2b = (u16*)(wsb + 33030144);        // 8,388,608 B
  u16* b2bb = (u16*)(wsb + 41418752);       // 8,388,608 B
  u16* w1pk = (u16*)(wsb + 49807360);       // 65,536 B
  u16* w2pk = (u16*)(wsb + 49872896);       // 65,536 B
  u16* wvpk = (u16*)(wsb + 49938432);       // 32,768 B
  u16* wepk = (u16*)(wsb + 49971200);       // 16,384 B
  float* mulr = (float*)(wsb + 49987584);   // 128 B
  float* accA = (float*)(wsb + 49987712);   // 8,192 B
  float* accB = (float*)(wsb + 49995904);   // 8,192 B

  hipMemsetAsync(accA, 0, 16384, stream);  // accA + accB
  prep_kernel<<<dim3(4, 16), 256, 0, stream>>>(Wa, Wk, Wv, W1, W2, w1pk, w2pk,
                                               wvpk, wepk);
  lngb_kernel<<<dim3(4096, 4), 256, 0, stream>>>(ln1_g, ln1_b, ln2_g, ln2_b,
                                                 g1b, b1bb, g2b, b2bb);
  stats_kernel<<<4096, 256, 0, stream>>>(x_in, accA);

  const float* xr = x_in;
  for (int d = 0; d < 4; ++d) {
    tb_kernel<<<dim3(128, 16), 256, 0, stream>>>(
        xr, g1b + (size_t)d * CHW, b1bb + (size_t)d * CHW, wepk + d * 2048,
        accA, accB, mulr, T);
    bconv_kernel<<<1024, 256, 0, stream>>>(T, Bbuf);
    attnc_kernel<<<256, 256, 0, stream>>>(
        xr, Bbuf, g1b + (size_t)d * CHW, b1bb + (size_t)d * CHW,
        wvpk + d * 4096, bv + d * 64, mulr, abf, accB, accA);
    ffn_kernel<<<2048, 256, 0, stream>>>(
        xr, xbuf, abf, g2b + (size_t)d * CHW, b2bb + (size_t)d * CHW,
        w1pk + d * 8192, b1 + d * 128, w2pk + d * 8192, b2 + d * 64, accB,
        accA);
    xr = xbuf;
  }
}

// Round 8
// 561.618 us; speedup vs baseline: 1.1751x; 1.0065x over previous
//
#include <hip/hip_runtime.h>

// Encoder: D=4, L=16, C=64, H=W=128.
// Math: softmax_j(A_i+B_j+ba)==softmax_j(B_j); attn identical for all i;
// B = conv5(h,Weff) as GEMM into 25 bf16 tap planes T + shift-add;
// a = Wv*(g1*(sum_j P_j r_j x_j - sum_j P_j r_j mu_j)+b1)+bv (V never
// materialized, R10). R11 (this): bf16 mirror xbf of x, produced free in
// ffn's epilogue (and stats_kernel for depth 0). tb and both attnc x
// passes read xbf (bf16) instead of f32 x: -64MB/depth reads for
// +32MB/depth writes (skipped last depth). Only ffn touches f32 x
// (residual chain keeps full precision). g1 keeps a bf16 mirror; other
// LN params read f32 (ws budget). u16x8 16B loads in tb/attnc.

#define HW 16384
#define CHW 1048576
#define NB 64  // stat buckets; each bucket = 32 floats = one 128B line

typedef unsigned short u16;
typedef __attribute__((ext_vector_type(8))) short bf16x8;
typedef __attribute__((ext_vector_type(8))) unsigned short u16x8;
typedef __attribute__((ext_vector_type(4))) float f32x4;

static __device__ __forceinline__ u16 f2bf(float f) {
  union { float f; unsigned int u; } v; v.f = f;
  unsigned int r = v.u + 0x7fffu + ((v.u >> 16) & 1u);
  return (u16)(r >> 16);
}
static __device__ __forceinline__ float bf2f(u16 h) {
  union { unsigned int u; float f; } v; v.u = ((unsigned int)h) << 16;
  return v.f;
}
// LN stats from bucketed accumulators, wave-parallel.
static __device__ __forceinline__ void ln_from_acc_wave(
    const float* acc, int l, int lane, float& mu, float& r) {
  const float invN = 1.f / 1048576.f;
  float2 v = *(const float2*)(acc + lane * 32 + 2 * l);
  float s = v.x, q = v.y;
#pragma unroll
  for (int off = 32; off > 0; off >>= 1) {
    s += __shfl_xor(s, off);
    q += __shfl_xor(q, off);
  }
  mu = s * invN;
  r = rsqrtf(q * invN - mu * mu + 1e-5f);
}

// ---- precompute bf16 MFMA fragment packs ----
__global__ __launch_bounds__(256) void prep_kernel(
    const float* __restrict__ Wa, const float* __restrict__ Wk,
    const float* __restrict__ Wv, const float* __restrict__ W1,
    const float* __restrict__ W2, u16* __restrict__ w1pk,
    u16* __restrict__ w2pk, u16* __restrict__ wvpk, u16* __restrict__ wepk) {
  int d = blockIdx.x;
  int t = blockIdx.y * 256 + threadIdx.x;  // 0..4095
  const int STR = 256 * 16;
  const float* WaK = Wa + ((size_t)d * 128 + 64) * 25;
  const float* Wkd = Wk + d * 4096;
  for (int idx = t; idx < 2048; idx += STR) {  // Weff: m=tap(32), k=ci(64)
    int frag = idx >> 9, lane = (idx >> 3) & 63, j = idx & 7;
    int mt = frag >> 1, kt = frag & 1;
    int tap = mt * 16 + (lane & 15);
    int ci = kt * 32 + (lane >> 4) * 8 + j;
    float s = 0.f;
    if (tap < 25)
      for (int co = 0; co < 64; ++co)
        s = fmaf(WaK[co * 25 + tap], Wkd[co * 64 + ci], s);
    wepk[d * 2048 + idx] = f2bf(s);
  }
  const float* Wvd = Wv + d * 4096;
  for (int idx = t; idx < 4096; idx += STR) {  // Wv: m=co(64), k=ci(64)
    int frag = idx >> 9, lane = (idx >> 3) & 63, j = idx & 7;
    int mt = frag >> 1, kt = frag & 1;
    int co = mt * 16 + (lane & 15);
    int ci = kt * 32 + (lane >> 4) * 8 + j;
    wvpk[d * 4096 + idx] = f2bf(Wvd[co * 64 + ci]);
  }
  const float* W1d = W1 + d * 8192;
  for (int idx = t; idx < 8192; idx += STR) {  // W1: m=o(128), k=ci(64)
    int frag = idx >> 9, lane = (idx >> 3) & 63, j = idx & 7;
    int mt = frag >> 1, kt = frag & 1;
    int o = mt * 16 + (lane & 15);
    int ci = kt * 32 + (lane >> 4) * 8 + j;
    w1pk[d * 8192 + idx] = f2bf(W1d[o * 64 + ci]);
  }
  const float* W2d = W2 + d * 8192;
  for (int idx = t; idx < 8192; idx += STR) {  // W2: m=c(64), k=o(128)
    int frag = idx >> 9, lane = (idx >> 3) & 63, j = idx & 7;
    int mt2 = frag >> 2, kt2 = frag & 3;
    int c = mt2 * 16 + (lane & 15);
    int o = kt2 * 32 + (lane >> 4) * 8 + j;
    w2pk[d * 8192 + idx] = f2bf(W2d[c * 128 + o]);
  }
}

// ---- convert ln1_g (all depths) to bf16 ----
__global__ __launch_bounds__(256) void lngb_kernel(
    const float* __restrict__ g1, u16* __restrict__ o1) {
  int idx = blockIdx.x * 256 + threadIdx.x;  // x4 elems
  float4 v = *(const float4*)(g1 + (size_t)idx * 4);
  ushort4 o;
  o.x = f2bf(v.x); o.y = f2bf(v.y); o.z = f2bf(v.z); o.w = f2bf(v.w);
  *(ushort4*)(o1 + (size_t)idx * 4) = o;
}

// ---- per-frame stats of x_in (bucketed) + xbf mirror write ----
__global__ __launch_bounds__(256) void stats_kernel(
    const float* __restrict__ xin, u16* __restrict__ xbf,
    float* __restrict__ acc) {
  int tid = threadIdx.x;
  size_t base = (size_t)blockIdx.x * 4096;
  const float4* in4 = (const float4*)(xin + base);
  float s = 0.f, q = 0.f;
#pragma unroll
  for (int k = 0; k < 4; ++k) {
    float4 v = in4[k * 256 + tid];
    ushort4 o;
    o.x = f2bf(v.x); o.y = f2bf(v.y); o.z = f2bf(v.z); o.w = f2bf(v.w);
    *(ushort4*)(xbf + base + (k * 256 + tid) * 4) = o;
    s += v.x + v.y + v.z + v.w;
    q = fmaf(v.x, v.x, q); q = fmaf(v.y, v.y, q);
    q = fmaf(v.z, v.z, q); q = fmaf(v.w, v.w, q);
  }
#pragma unroll
  for (int off = 32; off > 0; off >>= 1) {
    s += __shfl_down(s, off); q += __shfl_down(q, off);
  }
  __shared__ float ls[4], lq[4];
  int wave = tid >> 6;
  if ((tid & 63) == 0) { ls[wave] = s; lq[wave] = q; }
  __syncthreads();
  if (tid == 0) {
    int frame = blockIdx.x >> 8;
    int bkt = blockIdx.x & (NB - 1);
    atomicAdd(&acc[bkt * 32 + frame * 2], ls[0] + ls[1] + ls[2] + ls[3]);
    atomicAdd(&acc[bkt * 32 + frame * 2 + 1], lq[0] + lq[1] + lq[2] + lq[3]);
  }
}

// ---- LN1 + T GEMM (reads xbf bf16), 128 px/block ----
// LDS: hb[128][72] u16 chunk-rotated (18432 B).
__global__ __launch_bounds__(256) void tb_kernel(
    const u16* __restrict__ xbf, const u16* __restrict__ g,
    const float* __restrict__ bln, const u16* __restrict__ wep_g,
    const float* __restrict__ accA, float* __restrict__ accBz,
    float* __restrict__ mulr, u16* __restrict__ T) {
  __shared__ __align__(16) char lds[18432];
  u16* hb = (u16*)lds;
  int tid = threadIdx.x;
  int l = blockIdx.y;
  int p0 = blockIdx.x << 7;
  if (blockIdx.x == 0 && blockIdx.y == 0)
    for (int i = tid; i < NB * 32; i += 256) accBz[i] = 0.f;
  int lane = tid & 63;
  float mu, r;
  ln_from_acc_wave(accA, l, lane, mu, r);
  if (blockIdx.x == 0 && tid == 0) {
    mulr[2 * l] = mu;
    mulr[2 * l + 1] = r;
  }

  // stage h[px][ci]: thread = (pq: 8px, cg: 4c); u16x8 xbf/g loads
  {
    int pq = tid & 15, cg = tid >> 4;
    int px0 = pq * 8, c0 = cg * 4;
    float vv[4][8];
#pragma unroll
    for (int i = 0; i < 4; ++i) {
      int c = c0 + i;
      size_t gi = (((size_t)l * 64 + c) << 14) + p0 + px0;
      int li = (c << 14) + p0 + px0;
      u16x8 xv = *(const u16x8*)(xbf + gi);
      u16x8 gv = *(const u16x8*)(g + li);
      float4 bb0 = *(const float4*)(bln + li);
      float4 bb1 = *(const float4*)(bln + li + 4);
#pragma unroll
      for (int k = 0; k < 8; ++k) {
        float bbk = k < 4 ? ((const float*)&bb0)[k] : ((const float*)&bb1)[k - 4];
        vv[i][k] = (bf2f(xv[k]) - mu) * r * bf2f(gv[k]) + bbk;
      }
    }
#pragma unroll
    for (int k = 0; k < 8; ++k) {
      int row = px0 + k;
      int col = ((((c0 >> 3) + (row >> 2)) & 7) << 3) | (c0 & 7);
      ushort4 hv;
      hv.x = f2bf(vv[0][k]); hv.y = f2bf(vv[1][k]);
      hv.z = f2bf(vv[2][k]); hv.w = f2bf(vv[3][k]);
      *(ushort4*)(hb + row * 72 + col) = hv;
    }
  }
  __syncthreads();

  int wv = tid >> 6;
  int ln15 = lane & 15, quad = lane >> 4;

  bf16x8 ah[2][2];
#pragma unroll
  for (int mt = 0; mt < 2; ++mt) {
    int px = (wv * 2 + mt) * 16 + ln15;
#pragma unroll
    for (int kt = 0; kt < 2; ++kt) {
      int slot = ((kt * 4 + quad) + (px >> 2)) & 7;
      ah[mt][kt] = *(const bf16x8*)(hb + px * 72 + (slot << 3));
    }
  }
  const bf16x8* weg = (const bf16x8*)wep_g;

  f32x4 accT[2][2];
#pragma unroll
  for (int mt = 0; mt < 2; ++mt)
#pragma unroll
    for (int nt = 0; nt < 2; ++nt) accT[mt][nt] = (f32x4){0.f, 0.f, 0.f, 0.f};
#pragma unroll
  for (int nt = 0; nt < 2; ++nt) {
    bf16x8 b0 = weg[(nt * 2 + 0) * 64 + lane];
    bf16x8 b1w = weg[(nt * 2 + 1) * 64 + lane];
#pragma unroll
    for (int mt = 0; mt < 2; ++mt) {
      accT[mt][nt] = __builtin_amdgcn_mfma_f32_16x16x32_bf16(
          ah[mt][0], b0, accT[mt][nt], 0, 0, 0);
      accT[mt][nt] = __builtin_amdgcn_mfma_f32_16x16x32_bf16(
          ah[mt][1], b1w, accT[mt][nt], 0, 0, 0);
    }
  }

#pragma unroll
  for (int mt = 0; mt < 2; ++mt) {
    int pxb = p0 + (wv * 2 + mt) * 16 + quad * 4;
#pragma unroll
    for (int nt = 0; nt < 2; ++nt) {
      int tap = nt * 16 + ln15;
      if (tap < 25) {
        ushort4 o;
        o.x = f2bf(accT[mt][nt][0]); o.y = f2bf(accT[mt][nt][1]);
        o.z = f2bf(accT[mt][nt][2]); o.w = f2bf(accT[mt][nt][3]);
        *(ushort4*)(T + (((size_t)l * 25 + tap) << 14) + pxb) = o;
      }
    }
  }
}

// ---- B[l][p] = sum_tap T[l][tap][p + off(tap)] (T bf16) ----
__global__ __launch_bounds__(256) void bconv_kernel(
    const u16* __restrict__ T, float* __restrict__ B) {
  int gid = blockIdx.x * 256 + threadIdx.x;
  int l = gid >> 14, p = gid & 16383;
  int y = p >> 7, xx = p & 127;
  float s = 0.f;
#pragma unroll
  for (int dy = 0; dy < 5; ++dy) {
    int yy = y + dy - 2;
    if (yy < 0 || yy > 127) continue;
#pragma unroll
    for (int dx = 0; dx < 5; ++dx) {
      int xc = xx + dx - 2;
      if (xc < 0 || xc > 127) continue;
      s += bf2f(T[(((size_t)l * 25 + dy * 5 + dx) << 14) + (yy << 7) + xc]);
    }
  }
  B[gid] = s;
}

// ---- fused softmax + hbar + Wv-GEMM -> a (bf16) + stats of (x+a) ----
// all x reads from bf16 mirror. 64px tile/block, grid 256.
__global__ __launch_bounds__(256) void attnc_kernel(
    const u16* __restrict__ xbf, const float* __restrict__ B,
    const u16* __restrict__ g1, const float* __restrict__ b1g,
    const u16* __restrict__ wvp_g, const float* __restrict__ bv,
    const float* __restrict__ mulr, u16* __restrict__ abf,
    float* __restrict__ accB, float* __restrict__ accAz) {
  __shared__ float Prl[16][64];
  __shared__ float scal[64];
  __shared__ __align__(16) u16 hb[64 * 72];
  __shared__ float lsq[4][32];
  int tid = threadIdx.x;
  int p0 = blockIdx.x << 6;
  if (blockIdx.x == 0)  // zero accA buckets for ffn
    for (int i = tid; i < NB * 32; i += 256) accAz[i] = 0.f;

  // phase A: softmax weights (threads 0..63 own one px each)
  if (tid < 64) {
    float bj[16], m = -1e30f;
#pragma unroll
    for (int j = 0; j < 16; ++j) {
      bj[j] = B[(j << 14) + p0 + tid];
      m = fmaxf(m, bj[j]);
    }
    float sum = 0.f;
#pragma unroll
    for (int j = 0; j < 16; ++j) {
      bj[j] = __expf(bj[j] - m);
      sum += bj[j];
    }
    float inv = 1.f / sum;
    float sc = 0.f;
#pragma unroll
    for (int j = 0; j < 16; ++j) {
      float mu_j = mulr[2 * j], r_j = mulr[2 * j + 1];
      float prl = bj[j] * inv * r_j;
      Prl[j][tid] = prl;
      sc = fmaf(prl, mu_j, sc);
    }
    scal[tid] = sc;
  }
  __syncthreads();

  // phase B: xbar = sum_j Prl[j]*xbf_j ; hbar = g1*(xbar-scal)+b1 -> hb
  // thread = (c2: 2c, pxg: 8px); u16x8 loads
  {
    int c2 = tid >> 3, pxg = tid & 7;
    int px0 = pxg * 8;
    float xbar[2][8];
#pragma unroll
    for (int cc = 0; cc < 2; ++cc)
#pragma unroll
      for (int k = 0; k < 8; ++k) xbar[cc][k] = 0.f;
#pragma unroll
    for (int j = 0; j < 16; ++j) {
      float p8[8];
#pragma unroll
      for (int k = 0; k < 8; ++k) p8[k] = Prl[j][px0 + k];
#pragma unroll
      for (int cc = 0; cc < 2; ++cc) {
        int c = cc * 32 + c2;
        u16x8 xv =
            *(const u16x8*)(xbf + (((size_t)j * 64 + c) << 14) + p0 + px0);
#pragma unroll
        for (int k = 0; k < 8; ++k)
          xbar[cc][k] = fmaf(p8[k], bf2f(xv[k]), xbar[cc][k]);
      }
    }
    float sc8[8];
#pragma unroll
    for (int k = 0; k < 8; ++k) sc8[k] = scal[px0 + k];
#pragma unroll
    for (int cc = 0; cc < 2; ++cc) {
      int c = cc * 32 + c2;
      int li = (c << 14) + p0 + px0;
      u16x8 g8 = *(const u16x8*)(g1 + li);
      float4 b0 = *(const float4*)(b1g + li);
      float4 b1v = *(const float4*)(b1g + li + 4);
#pragma unroll
      for (int k = 0; k < 8; ++k) {
        float bbk = k < 4 ? ((const float*)&b0)[k] : ((const float*)&b1v)[k - 4];
        float hv = bf2f(g8[k]) * (xbar[cc][k] - sc8[k]) + bbk;
        int row = px0 + k;
        int col = ((((c >> 3) + (row >> 2)) & 7) << 3) | (c & 7);
        hb[row * 72 + col] = f2bf(hv);
      }
    }
  }
  __syncthreads();

  // phase C: a = Wv*hbar + bv (MFMA); wave owns 16 px
  int wv = tid >> 6, lane = tid & 63;
  int ln15 = lane & 15, quad = lane >> 4;
  int px = wv * 16 + ln15;
  bf16x8 ah[2];
#pragma unroll
  for (int kt = 0; kt < 2; ++kt) {
    int slot = ((kt * 4 + quad) + (px >> 2)) & 7;
    ah[kt] = *(const bf16x8*)(hb + px * 72 + (slot << 3));
  }
  const bf16x8* wvg = (const bf16x8*)wvp_g;
  f32x4 accV[4];
#pragma unroll
  for (int nt = 0; nt < 4; ++nt) accV[nt] = (f32x4){0.f, 0.f, 0.f, 0.f};
#pragma unroll
  for (int nt = 0; nt < 4; ++nt) {
    bf16x8 b0 = wvg[(nt * 2 + 0) * 64 + lane];
    bf16x8 b1w = wvg[(nt * 2 + 1) * 64 + lane];
    accV[nt] = __builtin_amdgcn_mfma_f32_16x16x32_bf16(ah[0], b0, accV[nt],
                                                       0, 0, 0);
    accV[nt] = __builtin_amdgcn_mfma_f32_16x16x32_bf16(ah[1], b1w, accV[nt],
                                                       0, 0, 0);
  }
  int pxb = p0 + wv * 16 + quad * 4;
  float av[4][4];
#pragma unroll
  for (int nt = 0; nt < 4; ++nt) {
    int c = nt * 16 + ln15;
    float bvc = bv[c];
    ushort4 o;
    av[nt][0] = accV[nt][0] + bvc; o.x = f2bf(av[nt][0]);
    av[nt][1] = accV[nt][1] + bvc; o.y = f2bf(av[nt][1]);
    av[nt][2] = accV[nt][2] + bvc; o.z = f2bf(av[nt][2]);
    av[nt][3] = accV[nt][3] + bvc; o.w = f2bf(av[nt][3]);
    *(ushort4*)(abf + ((size_t)c << 14) + pxb) = o;
  }

  // phase D: per-frame stats of (xbf + a)
  float sf[16], qf[16];
#pragma unroll
  for (int f = 0; f < 16; ++f) {
    float s = 0.f, q = 0.f;
#pragma unroll
    for (int nt = 0; nt < 4; ++nt) {
      int c = nt * 16 + ln15;
      ushort4 xv =
          *(const ushort4*)(xbf + (((size_t)f * 64 + c) << 14) + pxb);
      float v0 = bf2f(xv.x) + av[nt][0], v1 = bf2f(xv.y) + av[nt][1];
      float v2 = bf2f(xv.z) + av[nt][2], v3 = bf2f(xv.w) + av[nt][3];
      s += v0 + v1 + v2 + v3;
      q = fmaf(v0, v0, q); q = fmaf(v1, v1, q);
      q = fmaf(v2, v2, q); q = fmaf(v3, v3, q);
    }
    sf[f] = s; qf[f] = q;
  }
#pragma unroll
  for (int off = 32; off > 0; off >>= 1) {
#pragma unroll
    for (int f = 0; f < 16; ++f) {
      sf[f] += __shfl_down(sf[f], off);
      qf[f] += __shfl_down(qf[f], off);
    }
  }
  if (lane == 0) {
#pragma unroll
    for (int f = 0; f < 16; ++f) {
      lsq[wv][2 * f] = sf[f];
      lsq[wv][2 * f + 1] = qf[f];
    }
  }
  __syncthreads();
  if (tid < 32) {
    int bkt = blockIdx.x & (NB - 1);
    atomicAdd(&accB[bkt * 32 + tid],
              lsq[0][tid] + lsq[1][tid] + lsq[2][tid] + lsq[3][tid]);
  }
}

// ---- fused attn-add + LN2 + FFN + residual + stats, 128 px/block ----
// LDS: xa[64][132] f32 (33792) | hb[128][72] rot (18432) / f1 overlays.
// Epilogue also emits bf16 mirror xbf (when wrbf).
__global__ __launch_bounds__(256) void ffn_kernel(
    const float* __restrict__ xr, float* __restrict__ xw,
    u16* __restrict__ xbfw, const u16* __restrict__ ap,
    const float* __restrict__ g, const float* __restrict__ bln,
    const u16* __restrict__ w1p_g, const float* __restrict__ b1,
    const u16* __restrict__ w2p_g, const float* __restrict__ b2,
    const float* __restrict__ accB, float* __restrict__ accA, int wrbf) {
  __shared__ __align__(16) char lds[66560];
  float* xaf = (float*)lds;       // [64 c][132 px-padded] f32
  u16* hb = (u16*)(lds + 33792);  // [128][72] chunk-rotated
  u16* f1 = (u16*)(lds + 33792);  // [128][128] swz, overlays hb

  int tid = threadIdx.x;
  int P0 = blockIdx.x << 7;
  int l = P0 >> 14;
  int p0 = P0 & 16383;
  int lane = tid & 63;
  float mu, r;
  ln_from_acc_wave(accB, l, lane, mu, r);

  // stage: xa = x + a -> LDS f32; h = LN(xa) -> hb (chunk-rotated)
#pragma unroll
  for (int it = 0; it < 2; ++it) {
    int pq = tid & 31, cg = (tid >> 5) + it * 8;
    int px = pq * 4, c0 = cg * 4;
    float vv[4][4];
#pragma unroll
    for (int i = 0; i < 4; ++i) {
      int c = c0 + i;
      size_t gi = (((size_t)l * 64 + c) << 14) + p0 + px;
      int li = (c << 14) + p0 + px;
      float4 xv = *(const float4*)(xr + gi);
      ushort4 av4 = *(const ushort4*)(ap + li);
      float4 gv = *(const float4*)(g + li);
      float4 bb = *(const float4*)(bln + li);
      float4 s4;
      s4.x = xv.x + bf2f(av4.x); s4.y = xv.y + bf2f(av4.y);
      s4.z = xv.z + bf2f(av4.z); s4.w = xv.w + bf2f(av4.w);
      *(float4*)(xaf + c * 132 + px) = s4;
      vv[i][0] = (s4.x - mu) * r * gv.x + bb.x;
      vv[i][1] = (s4.y - mu) * r * gv.y + bb.y;
      vv[i][2] = (s4.z - mu) * r * gv.z + bb.z;
      vv[i][3] = (s4.w - mu) * r * gv.w + bb.w;
    }
#pragma unroll
    for (int k = 0; k < 4; ++k) {
      int row = px + k;
      int col = ((((c0 >> 3) + (row >> 2)) & 7) << 3) | (c0 & 7);
      ushort4 hv;
      hv.x = f2bf(vv[0][k]); hv.y = f2bf(vv[1][k]);
      hv.z = f2bf(vv[2][k]); hv.w = f2bf(vv[3][k]);
      *(ushort4*)(hb + row * 72 + col) = hv;
    }
  }
  __syncthreads();

  int wv = tid >> 6;
  int ln15 = lane & 15, quad = lane >> 4;

  bf16x8 bh[2][2];
#pragma unroll
  for (int nt = 0; nt < 2; ++nt) {
    int px = (wv * 2 + nt) * 16 + ln15;
#pragma unroll
    for (int kt = 0; kt < 2; ++kt) {
      int slot = ((kt * 4 + quad) + (px >> 2)) & 7;
      bh[nt][kt] = *(const bf16x8*)(hb + px * 72 + (slot << 3));
    }
  }
  __syncthreads();  // all hb reads drained; f1 may now overwrite

  const bf16x8* w1g = (const bf16x8*)w1p_g;
  const bf16x8* w2g = (const bf16x8*)w2p_g;

  // GEMM1 per o-tile mt
#pragma unroll
  for (int mt = 0; mt < 8; ++mt) {
    bf16x8 a1a = w1g[(mt * 2 + 0) * 64 + lane];
    bf16x8 a1b = w1g[(mt * 2 + 1) * 64 + lane];
    f32x4 acc[2];
    acc[0] = (f32x4){0.f, 0.f, 0.f, 0.f};
    acc[1] = (f32x4){0.f, 0.f, 0.f, 0.f};
#pragma unroll
    for (int nt = 0; nt < 2; ++nt) {
      acc[nt] = __builtin_amdgcn_mfma_f32_16x16x32_bf16(a1a, bh[nt][0],
                                                        acc[nt], 0, 0, 0);
      acc[nt] = __builtin_amdgcn_mfma_f32_16x16x32_bf16(a1b, bh[nt][1],
                                                        acc[nt], 0, 0, 0);
    }
    int o0 = mt * 16 + quad * 4;
    float4 b1v = *(const float4*)(b1 + o0);
#pragma unroll
    for (int nt = 0; nt < 2; ++nt) {
      int px = (wv * 2 + nt) * 16 + ln15;
      int swz = (px & 7) * 8;
      float fv[4];
#pragma unroll
      for (int rj = 0; rj < 4; ++rj) {
        float f = acc[nt][rj] + ((const float*)&b1v)[rj];
        fv[rj] = fmaxf(f, 0.01f * f);
      }
      int col = ((o0 & ~7) ^ swz) + (o0 & 7);
      ushort4 ov;
      ov.x = f2bf(fv[0]); ov.y = f2bf(fv[1]);
      ov.z = f2bf(fv[2]); ov.w = f2bf(fv[3]);
      *(ushort4*)(f1 + px * 128 + col) = ov;
    }
  }
  __syncthreads();

  // GEMM2 transposed
  bf16x8 a2[2][4];
#pragma unroll
  for (int mt = 0; mt < 2; ++mt) {
    int px = (wv * 2 + mt) * 16 + ln15;
    int swz = (px & 7) * 8;
#pragma unroll
    for (int kt = 0; kt < 4; ++kt)
      a2[mt][kt] =
          *(const bf16x8*)(f1 + px * 128 + ((kt * 32 + quad * 8) ^ swz));
  }
  f32x4 acc2[2][4];
#pragma unroll
  for (int mt = 0; mt < 2; ++mt)
#pragma unroll
    for (int nt = 0; nt < 4; ++nt) acc2[mt][nt] = (f32x4){0.f, 0.f, 0.f, 0.f};
#pragma unroll
  for (int nt = 0; nt < 4; ++nt) {
    bf16x8 bw[4];
#pragma unroll
    for (int kt = 0; kt < 4; ++kt) bw[kt] = w2g[(nt * 4 + kt) * 64 + lane];
#pragma unroll
    for (int mt = 0; mt < 2; ++mt)
#pragma unroll
      for (int kt = 0; kt < 4; ++kt)
        acc2[mt][nt] = __builtin_amdgcn_mfma_f32_16x16x32_bf16(
            a2[mt][kt], bw[kt], acc2[mt][nt], 0, 0, 0);
  }

  // epilogue: v = xa(LDS) + ffn_out -> xw (+ xbf mirror); stats
  float s = 0.f, q = 0.f;
#pragma unroll
  for (int mt = 0; mt < 2; ++mt) {
    int pxl = (wv * 2 + mt) * 16 + quad * 4;
#pragma unroll
    for (int nt = 0; nt < 4; ++nt) {
      int c = nt * 16 + ln15;
      float b2c = b2[c];
      const float* xac = xaf + c * 132 + pxl;
      float4 v;
      v.x = xac[0] + acc2[mt][nt][0] + b2c;
      v.y = xac[1] + acc2[mt][nt][1] + b2c;
      v.z = xac[2] + acc2[mt][nt][2] + b2c;
      v.w = xac[3] + acc2[mt][nt][3] + b2c;
      size_t gi = (((size_t)l * 64 + c) << 14) + p0 + pxl;
      *(float4*)(xw + gi) = v;
      if (wrbf) {
        ushort4 o;
        o.x = f2bf(v.x); o.y = f2bf(v.y); o.z = f2bf(v.z); o.w = f2bf(v.w);
        *(ushort4*)(xbfw + gi) = o;
      }
      s += v.x + v.y + v.z + v.w;
      q = fmaf(v.x, v.x, q); q = fmaf(v.y, v.y, q);
      q = fmaf(v.z, v.z, q); q = fmaf(v.w, v.w, q);
    }
  }
#pragma unroll
  for (int off = 32; off > 0; off >>= 1) {
    s += __shfl_down(s, off); q += __shfl_down(q, off);
  }
  if (lane == 0) {
    int bkt = blockIdx.x & (NB - 1);
    atomicAdd(&accA[bkt * 32 + l * 2], s);
    atomicAdd(&accA[bkt * 32 + l * 2 + 1], q);
  }
}

extern "C" void kernel_launch(void* const* d_in, const int* in_sizes, int n_in,
                              void* d_out, int out_size, void* d_ws,
                              size_t ws_size, hipStream_t stream) {
  const float* x_in = (const float*)d_in[0];
  const float* ln1_g = (const float*)d_in[1];
  const float* ln1_b = (const float*)d_in[2];
  const float* Wk = (const float*)d_in[5];
  const float* Wv = (const float*)d_in[7];
  const float* bv = (const float*)d_in[8];
  const float* Wa = (const float*)d_in[9];
  const float* ln2_g = (const float*)d_in[11];
  const float* ln2_b = (const float*)d_in[12];
  const float* W1 = (const float*)d_in[13];
  const float* b1 = (const float*)d_in[14];
  const float* W2 = (const float*)d_in[15];
  const float* b2 = (const float*)d_in[16];

  float* xbuf = (float*)d_out;
  char* wsb = (char*)d_ws;
  u16* xbf = (u16*)wsb;                     // 33,554,432 B
  u16* T = (u16*)(wsb + 33554432);          // 13,107,200 B
  u16* abf = (u16*)(wsb + 46661632);        // 2,097,152 B
  float* Bbuf = (float*)(wsb + 48758784);   // 1,048,576 B
  u16* g1b = (u16*)(wsb + 49807360);        // 8,388,608 B
  u16* w1pk = (u16*)(wsb + 58195968);       // 65,536 B
  u16* w2pk = (u16*)(wsb + 58261504);       // 65,536 B
  u16* wvpk = (u16*)(wsb + 58327040);       // 32,768 B
  u16* wepk = (u16*)(wsb + 58359808);       // 16,384 B
  float* mulr = (float*)(wsb + 58376192);   // 128 B
  float* accA = (float*)(wsb + 58376320);   // 8,192 B
  float* accB = (float*)(wsb + 58384512);   // 8,192 B

  hipMemsetAsync(accA, 0, 16384, stream);  // accA + accB
  prep_kernel<<<dim3(4, 16), 256, 0, stream>>>(Wa, Wk, Wv, W1, W2, w1pk, w2pk,
                                               wvpk, wepk);
  lngb_kernel<<<4096, 256, 0, stream>>>(ln1_g, g1b);
  stats_kernel<<<4096, 256, 0, stream>>>(x_in, xbf, accA);

  const float* xr = x_in;
  for (int d = 0; d < 4; ++d) {
    tb_kernel<<<dim3(128, 16), 256, 0, stream>>>(
        xbf, g1b + (size_t)d * CHW, ln1_b + (size_t)d * CHW, wepk + d * 2048,
        accA, accB, mulr, T);
    bconv_kernel<<<1024, 256, 0, stream>>>(T, Bbuf);
    attnc_kernel<<<256, 256, 0, stream>>>(
        xbf, Bbuf, g1b + (size_t)d * CHW, ln1_b + (size_t)d * CHW,
        wvpk + d * 4096, bv + d * 64, mulr, abf, accB, accA);
    ffn_kernel<<<2048, 256, 0, stream>>>(
        xr, xbuf, xbf, abf, ln2_g + (size_t)d * CHW, ln2_b + (size_t)d * CHW,
        w1pk + d * 8192, b1 + d * 128, w2pk + d * 8192, b2 + d * 64, accB,
        accA, d < 3 ? 1 : 0);
    xr = xbuf;
  }
}